// Round 10
// baseline (399.524 us; speedup 1.0000x reference)
//
#include <hip/hip_runtime.h>
#include <math.h>

#define BB   4
#define CC   256
#define HH   96
#define WW   96
#define OO   256
#define HW   9216        // HH*WW
#define KDIM 2304        // CC*9
#define OFFC 18
#define NKC  36          // K chunks of 64

// K ordering for the deform GEMM (split path): k' = tap*256 + c  (tap-major).
// V, Wb, and offset_meta's A/W staging all use k'; GEMM is ordering-agnostic.

typedef short bf16x8 __attribute__((ext_vector_type(8)));
typedef float f32x4  __attribute__((ext_vector_type(4)));
typedef unsigned int u32x2 __attribute__((ext_vector_type(2)));
typedef unsigned int u32x4 __attribute__((ext_vector_type(4)));

// ---- ws layout (split path) ----
#define WS_V_SZ    (36864ull * 4608ull)               // V bf16 [p][k'], row 4608B, pre-swizzled
#define WS_WB_OFF  WS_V_SZ
#define WS_WB_SZ   (256ull * 4608ull)                 // W bf16 [o][k'], pre-swizzled
#define WS_META_OFF (WS_WB_OFF + WS_WB_SZ)
#define WS_META_SZ (4ull * 9ull * 9216ull * 16ull)    // uint4 per (b,tap,p)
#define WS_NEED    (WS_META_OFF + WS_META_SZ)         // ~176.4 MB

__device__ __forceinline__ unsigned short f2bfu(float f) {
    unsigned u = __float_as_uint(f);
    unsigned r = (u + 0x7fffu + ((u >> 16) & 1u)) >> 16;   // RNE
    return (unsigned short)r;
}
__device__ __forceinline__ unsigned pack2(float lo, float hi) {
    return (unsigned)f2bfu(lo) | ((unsigned)f2bfu(hi) << 16);
}
__device__ __forceinline__ void gload16(const void* g, void* l) {
    __builtin_amdgcn_global_load_lds((const __attribute__((address_space(1))) void*)g,
                                     (__attribute__((address_space(3))) void*)l, 16, 0, 0);
}
__device__ __forceinline__ void gload4(const void* g, void* l) {
    __builtin_amdgcn_global_load_lds((const __attribute__((address_space(1))) void*)g,
                                     (__attribute__((address_space(3))) void*)l, 4, 0, 0);
}

__device__ __forceinline__ uint4 make_meta(int pr, int t, float dy, float dx) {
    int oh = pr / WW, ow = pr - oh * WW;
    float py = (float)(oh - 1 + t / 3) + dy;
    float px = (float)(ow - 1 + (t % 3)) + dx;
    float y0f = floorf(py), x0f = floorf(px);
    int y0 = (int)y0f, x0 = (int)x0f;
    float ly = py - y0f, lx = px - x0f;
    float wy0 = (y0 >= 0 && y0 < HH) ? 1.f - ly : 0.f;
    float wy1 = (y0 + 1 >= 0 && y0 + 1 < HH) ? ly : 0.f;
    float u0 = (x0 >= 0 && x0 < WW) ? 1.f - lx : 0.f;
    float u1 = (x0 + 1 >= 0 && x0 + 1 < WW) ? lx : 0.f;
    int pb = min(max(x0, 0), WW - 2);
    float s0, s1;
    if (x0 < 0)           { s0 = u1; s1 = 0.f; }
    else if (x0 > WW - 2) { s0 = 0.f; s1 = u0; }
    else                  { s0 = u0; s1 = u1; }
    int cy0 = min(max(y0, 0), HH - 1);
    int cy1 = min(max(y0 + 1, 0), HH - 1);
    uint4 m;
    m.x = (unsigned)(cy0 * WW + pb);
    m.y = (unsigned)(cy1 * WW + pb);
    m.z = pack2(wy0 * s0, wy0 * s1);
    m.w = pack2(wy1 * s0, wy1 * s1);
    return m;
}

// ================= SPLIT PATH =================

// ---- Kernel A: offset conv via MFMA (64p x 32oc tile) + direct meta emission ----
// k' ordering: chunk kc -> tap = kc>>2, c-base = (kc&3)*64
__global__ __launch_bounds__(256)
void offset_meta_kernel(const float* __restrict__ x,
                        const float* __restrict__ w_off,
                        const float* __restrict__ b_off,
                        uint4* __restrict__ meta_ws)
{
    __shared__ __align__(16) char Asw[64 * 128];
    __shared__ __align__(16) char Wl[32 * 128];
    __shared__ float Dsh[64][21];

    const int tid = threadIdx.x;
    const int fin = ((blockIdx.x & 7) * 72) + (blockIdx.x >> 3);  // XCD-chunked (576 = 8*72)
    const int b   = fin / 144;
    const int pr0 = (fin % 144) * 64;
    const float* xb = x + (size_t)b * CC * HW;

    const int l15 = tid & 15;
    const int l4  = (tid >> 4) & 3;
    const int wav = tid >> 6;
    const int sp  = tid & 63;       // A staging: p row
    const int kq  = tid >> 6;       // A staging: c quarter (16 c)
    const int so  = tid >> 3;       // W staging: o row 0..31
    const int sq  = tid & 7;        // W staging: q group (8 c)

    const int prg = pr0 + sp;
    const int oh = prg / WW, ow = prg - (prg / WW) * WW;

    f32x4 acc[2];
    acc[0] = (f32x4){0.f, 0.f, 0.f, 0.f};
    acc[1] = (f32x4){0.f, 0.f, 0.f, 0.f};

    for (int kc = 0; kc < NKC; ++kc) {
        const int tap = kc >> 2;
        const int cb  = (kc & 3) * 64;
        // stage W (fp32 -> bf16, swizzled); rows 18..31 zero. w_off[so][c][tap], stride-9
        {
            uint4 pk;
            if (so < OFFC) {
                const float* wr = w_off + (size_t)so * KDIM + (cb + sq * 8) * 9 + tap;
                float wv[8];
                #pragma unroll
                for (int i = 0; i < 8; ++i) wv[i] = wr[i * 9];
                pk.x = pack2(wv[0], wv[1]); pk.y = pack2(wv[2], wv[3]);
                pk.z = pack2(wv[4], wv[5]); pk.w = pack2(wv[6], wv[7]);
            } else { pk.x = pk.y = pk.z = pk.w = 0u; }
            *(uint4*)(Wl + so * 128 + ((sq * 16) ^ ((so & 7) << 4))) = pk;
        }
        // stage A: static-tap gather, 16 c per thread (fixed tap -> bounds once)
        {
            int iy = oh + tap / 3 - 1;
            int ix = ow + tap % 3 - 1;
            bool ok = (iy >= 0) & (iy < HH) & (ix >= 0) & (ix < WW);
            const float* xp = xb + (size_t)(cb + kq * 16) * HW + iy * WW + ix;
            float v[16];
            #pragma unroll
            for (int e = 0; e < 16; ++e)
                v[e] = ok ? xp[(size_t)e * HW] : 0.f;
            char* arow = Asw + sp * 128;
            unsigned swz = (unsigned)((sp & 7) << 4);
            uint4 p0, p1;
            p0.x = pack2(v[0], v[1]);   p0.y = pack2(v[2], v[3]);
            p0.z = pack2(v[4], v[5]);   p0.w = pack2(v[6], v[7]);
            p1.x = pack2(v[8], v[9]);   p1.y = pack2(v[10], v[11]);
            p1.z = pack2(v[12], v[13]); p1.w = pack2(v[14], v[15]);
            *(uint4*)(arow + (((unsigned)(kq * 32 + 0)) ^ swz)) = p0;
            *(uint4*)(arow + (((unsigned)(kq * 32 + 16)) ^ swz)) = p1;
        }
        __syncthreads();
        // MFMA: wave handles p-frag wav*16, oc-frags 0..1
        {
            int p_loc = wav * 16 + l15;
            unsigned aswz = (unsigned)((p_loc & 7) << 4);
            #pragma unroll
            for (int ks = 0; ks < 2; ++ks) {
                bf16x8 a = *(const bf16x8*)(Asw + p_loc * 128 + ((ks * 64 + l4 * 16) ^ aswz));
                #pragma unroll
                for (int g = 0; g < 2; ++g) {
                    int o_loc = g * 16 + l15;
                    bf16x8 bw = *(const bf16x8*)(Wl + o_loc * 128 +
                                                 ((ks * 64 + l4 * 16) ^ ((o_loc & 7) << 4)));
                    acc[g] = __builtin_amdgcn_mfma_f32_16x16x32_bf16(a, bw, acc[g], 0, 0, 0);
                }
            }
        }
        __syncthreads();
    }

    // D -> LDS (rows p, cols oc<18), add bias
    #pragma unroll
    for (int g = 0; g < 2; ++g) {
        int o = g * 16 + l15;
        if (o < OFFC) {
            float bo = b_off[o];
            #pragma unroll
            for (int r = 0; r < 4; ++r)
                Dsh[wav * 16 + l4 * 4 + r][o] = acc[g][r] + bo;
        }
    }
    __syncthreads();
    // meta: 9 taps x 64 positions
    for (int s = tid; s < 9 * 64; s += 256) {
        int t = s >> 6, pl = s & 63;
        int pr = pr0 + pl;
        float dy = Dsh[pl][2 * t];
        float dx = Dsh[pl][2 * t + 1];
        meta_ws[((size_t)b * 9 + t) * HW + pr] = make_meta(pr, t, dy, dx);
    }
}

// ---- Kernel B: w_dc fp32 -> bf16 pre-swizzled, k' = tap*256 + c ----
__global__ __launch_bounds__(256)
void wconv_kernel(const float* __restrict__ w_dc, char* __restrict__ wb)
{
    int idx = blockIdx.x * 256 + (int)threadIdx.x;   // 73728 = 256 o * 288 (36 chunk * 8 q)
    int o   = idx / 288;
    int rem = idx - o * 288;
    int ch  = rem >> 3;          // chunk 0..35
    int q   = rem & 7;           // q group
    int tap = ch >> 2;
    int c0  = (ch & 3) * 64 + q * 8;
    const float* wr = w_dc + (size_t)o * KDIM + (size_t)c0 * 9 + tap;
    float wv[8];
    #pragma unroll
    for (int i = 0; i < 8; ++i) wv[i] = wr[i * 9];
    uint4 pk;
    pk.x = pack2(wv[0], wv[1]); pk.y = pack2(wv[2], wv[3]);
    pk.z = pack2(wv[4], wv[5]); pk.w = pack2(wv[6], wv[7]);
    *(uint4*)(wb + (size_t)o * 4608 + ch * 128 + ((q * 16) ^ ((o & 7) << 4))) = pk;
}

// ---- Kernel C: bilinear gather via global_load_lds DMA staging ----
// block = (pt, kc): 128 positions x 64 channels of ONE tap; meta in registers.
// Per 4-channel chunk a wave issues 16 DMA loads (per-lane scattered global
// src -> wave-uniform LDS slab + lane*4), double-buffered, counted vmcnt(16);
// combine reads Stage from LDS (2-way bank = free). No barriers in the loop —
// each wave consumes only its own staged rows. In-flight state lives in the
// vmcnt queue, not VGPRs (the compiler refused >8 loads in flight, r8/r9).
__global__ __launch_bounds__(256)
void gather_kernel7(const float* __restrict__ x,
                    const uint4* __restrict__ meta_ws,
                    char* __restrict__ Vg)
{
    __shared__ uint4 Lmeta[128];
    __shared__ __align__(16) char Vl[128 * 128];       // [p][64 k' bf16], swizzled
    __shared__ __align__(16) float Stage[2][4][16][64]; // [buf][wave][e*4+q][lane] 32KB

    int bid = blockIdx.x;                          // 10368 = 8 * 1296
    int fin = (bid & 7) * 1296 + (bid >> 3);       // XCD-chunked
    int ptg = fin / NKC;                           // p-tile 0..287
    int kc  = fin - ptg * NKC;                     // k' chunk 0..35
    int tap = kc >> 2;
    int b   = ptg / 72;
    int tid = threadIdx.x;

    if (tid < 128)
        Lmeta[tid] = meta_ws[((size_t)b * 9 + tap) * HW + (ptg % 72) * 128 + tid];
    __syncthreads();

    const int j    = tid & 127;
    const int kh   = tid >> 7;
    const int wav  = tid >> 6;
    const int lane = tid & 63;
    uint4 m = Lmeta[j];
    const float wa0 = __uint_as_float(m.z << 16);
    const float wa1 = __uint_as_float(m.z & 0xffff0000u);
    const float wb0 = __uint_as_float(m.w << 16);
    const float wb1 = __uint_as_float(m.w & 0xffff0000u);

    const int c0 = (kc & 3) * 64 + kh * 32;
    const float* xA = x + ((size_t)b * CC + c0) * HW + m.x;
    const float* xB = x + ((size_t)b * CC + c0) * HW + m.y;
    char* vrow = Vl + j * 128;
    const unsigned swz = (unsigned)((j & 7) << 4);

#define ISSUE(g, bi) {                                                \
        float* sb_ = &Stage[bi][wav][0][0];                           \
        _Pragma("unroll")                                             \
        for (int e = 0; e < 4; ++e) {                                 \
            const float* a_ = xA + (size_t)((g) * 4 + e) * HW;        \
            const float* q_ = xB + (size_t)((g) * 4 + e) * HW;        \
            gload4(a_,     sb_ + (e * 4 + 0) * 64);                   \
            gload4(a_ + 1, sb_ + (e * 4 + 1) * 64);                   \
            gload4(q_,     sb_ + (e * 4 + 2) * 64);                   \
            gload4(q_ + 1, sb_ + (e * 4 + 3) * 64);                   \
        } }

    ISSUE(0, 0);
    #pragma unroll
    for (int g = 0; g < 8; ++g) {                  // 8 chunks of 4 channels
        if (g < 7) {
            ISSUE(g + 1, (g + 1) & 1);
            asm volatile("s_waitcnt vmcnt(16)" ::: "memory");  // chunk g landed
        } else {
            asm volatile("s_waitcnt vmcnt(0)" ::: "memory");
        }
        const float* sb = &Stage[g & 1][wav][0][0];
        float v[4];
        #pragma unroll
        for (int e = 0; e < 4; ++e) {
            float A0 = sb[(e * 4 + 0) * 64 + lane];
            float A1 = sb[(e * 4 + 1) * 64 + lane];
            float B0 = sb[(e * 4 + 2) * 64 + lane];
            float B1 = sb[(e * 4 + 3) * 64 + lane];
            v[e] = fmaf(wa0, A0, fmaf(wa1, A1, fmaf(wb0, B0, wb1 * B1)));
        }
        u32x2 pk;
        pk.x = pack2(v[0], v[1]);
        pk.y = pack2(v[2], v[3]);
        *(u32x2*)(vrow + (((unsigned)(kh * 64 + g * 8)) ^ swz)) = pk;
    }
#undef ISSUE
    __syncthreads();

    // write-out: LDS (already-swizzled content) -> Vg rows, 128B per row chunk
    char* dst = Vg + (size_t)(ptg * 128) * 4608 + (size_t)kc * 128;
    #pragma unroll
    for (int i = 0; i < 4; ++i) {
        int idx = i * 256 + tid;
        int row = idx >> 3, colg = (idx & 7) * 16;
        *(uint4*)(dst + (size_t)row * 4608 + colg) =
            *(const uint4*)(Vl + row * 128 + colg);
    }
}

// ---- Kernel D: streaming GEMM, 2-phase double-buffered, global_load_lds ----
__global__ __launch_bounds__(256)
void gemm_kernel(const char* __restrict__ Vg, const char* __restrict__ Wb,
                 const float* __restrict__ b_dc, float* __restrict__ out)
{
    __shared__ __align__(16) char Ab[2][128 * 128];
    __shared__ __align__(16) char Bb[2][128 * 128];

    int bid = blockIdx.x;
    int swzb = (bid & 7) * 72 + (bid >> 3);   // both ot of a pt share an XCD
    int pt = swzb >> 1, ot = swzb & 1;
    int tid = threadIdx.x;
    int lane = tid & 63, wav = tid >> 6;
    const int l15 = tid & 15, l4 = (tid >> 4) & 3;
    const int wp = wav >> 1, wo = wav & 1;

    const char* Ag = Vg + (size_t)(pt * 128) * 4608;
    const char* Bg = Wb + (size_t)(ot * 128) * 4608;
    const int rsub = lane >> 3;
    const int csub = (lane & 7) * 16;

    f32x4 acc[4][4];
    #pragma unroll
    for (int f = 0; f < 4; ++f)
        #pragma unroll
        for (int g = 0; g < 4; ++g)
            acc[f][g] = (f32x4){0.f, 0.f, 0.f, 0.f};

#define STAGE(bufi, t) {                                                        \
        const char* ag = Ag + (size_t)(t) * 128;                                \
        const char* bg = Bg + (size_t)(t) * 128;                                \
        _Pragma("unroll")                                                       \
        for (int i = 0; i < 4; ++i) {                                           \
            int r0 = wav * 32 + i * 8;                                          \
            gload16(ag + (size_t)(r0 + rsub) * 4608 + csub, &Ab[bufi][r0 * 128]);\
            gload16(bg + (size_t)(r0 + rsub) * 4608 + csub, &Bb[bufi][r0 * 128]);\
        } }

    STAGE(0, 0);
    __syncthreads();

    int cur = 0;
    for (int t = 0; t < NKC; ++t) {
        if (t + 1 < NKC) STAGE(cur ^ 1, t + 1);
        #pragma unroll
        for (int ks = 0; ks < 2; ++ks) {
            bf16x8 a[4], bw[4];
            #pragma unroll
            for (int f = 0; f < 4; ++f) {
                int p_loc = wp * 64 + f * 16 + l15;
                a[f] = *(const bf16x8*)(Ab[cur] + p_loc * 128 +
                                        ((ks * 64 + l4 * 16) ^ ((p_loc & 7) << 4)));
            }
            #pragma unroll
            for (int g = 0; g < 4; ++g) {
                int o_loc = wo * 64 + g * 16 + l15;
                bw[g] = *(const bf16x8*)(Bb[cur] + o_loc * 128 +
                                         ((ks * 64 + l4 * 16) ^ ((o_loc & 7) << 4)));
            }
            #pragma unroll
            for (int f = 0; f < 4; ++f)
                #pragma unroll
                for (int g = 0; g < 4; ++g)
                    acc[f][g] = __builtin_amdgcn_mfma_f32_16x16x32_bf16(a[f], bw[g], acc[f][g], 0, 0, 0);
        }
        __syncthreads();
        cur ^= 1;
    }

    int b = pt / 72;
    int posr = (pt - b * 72) * 128;
    #pragma unroll
    for (int g = 0; g < 4; ++g) {
        int og = ot * 128 + wo * 64 + g * 16 + l15;
        float bias = b_dc[og];
        float* op = out + ((size_t)b * OO + og) * HW + posr + wp * 64 + l4 * 4;
        #pragma unroll
        for (int f = 0; f < 4; ++f) {
            f32x4 r = acc[f][g];
            float4 st;
            st.x = r[0] + bias; st.y = r[1] + bias;
            st.z = r[2] + bias; st.w = r[3] + bias;
            *(float4*)(op + f * 16) = st;
        }
    }
}

// ================= FALLBACK PATH (round-2, verified; self-consistent k ordering) =================

__global__ __launch_bounds__(256)
void offset_conv6_kernel(const float* __restrict__ x,
                         const float* __restrict__ w_off,
                         const float* __restrict__ b_off,
                         float* __restrict__ off)
{
    int bid   = blockIdx.x;
    int g     = bid % 3;
    int chunk = (bid / 3) % 36;
    int b     = bid / 108;
    int ocb   = g * 6;
    int pr    = chunk * 256 + (int)threadIdx.x;
    int oh    = pr / WW, ow = pr % WW;
    const float* xb = x + (size_t)b * CC * HW;

    float acc[6];
    #pragma unroll
    for (int i = 0; i < 6; ++i) acc[i] = b_off[ocb + i];

    bool interior = (oh >= 1) & (oh < HH - 1) & (ow >= 1) & (ow < WW - 1);
    if (interior) {
        const float* xp = xb + (oh - 1) * WW + (ow - 1);
        float xv[9];
        #pragma unroll
        for (int t = 0; t < 9; ++t) xv[t] = xp[(t / 3) * WW + (t % 3)];
        for (int c = 0; c < CC; ++c) {
            float xn[9];
            if (c + 1 < CC) {
                const float* xq = xp + (size_t)(c + 1) * HW;
                #pragma unroll
                for (int t = 0; t < 9; ++t) xn[t] = xq[(t / 3) * WW + (t % 3)];
            }
            #pragma unroll
            for (int i = 0; i < 6; ++i) {
                const float* wr = w_off + ((size_t)(ocb + i) * CC + c) * 9;
                #pragma unroll
                for (int t = 0; t < 9; ++t)
                    acc[i] = fmaf(xv[t], wr[t], acc[i]);
            }
            #pragma unroll
            for (int t = 0; t < 9; ++t) xv[t] = xn[t];
        }
    } else {
        for (int c = 0; c < CC; ++c) {
            const float* xc = xb + (size_t)c * HW;
            float xv[9];
            #pragma unroll
            for (int t = 0; t < 9; ++t) {
                int yy = oh + t / 3 - 1, xx = ow + t % 3 - 1;
                xv[t] = (yy >= 0 && yy < HH && xx >= 0 && xx < WW) ? xc[yy * WW + xx] : 0.f;
            }
            #pragma unroll
            for (int i = 0; i < 6; ++i) {
                const float* wr = w_off + ((size_t)(ocb + i) * CC + c) * 9;
                #pragma unroll
                for (int t = 0; t < 9; ++t)
                    acc[i] = fmaf(xv[t], wr[t], acc[i]);
            }
        }
    }
    #pragma unroll
    for (int i = 0; i < 6; ++i)
        off[((size_t)b * OFFC + ocb + i) * HW + pr] = acc[i];
}

__global__ __launch_bounds__(256)
void deform_mfma_kernel(const float* __restrict__ x,
                        const float* __restrict__ off,
                        const float* __restrict__ w_dc,
                        const float* __restrict__ b_dc,
                        float* __restrict__ out)
{
    __shared__ __align__(16) char VlB[128 * 128];
    __shared__ __align__(16) char WlB[128 * 128];
    __shared__ uint4 meta[9][128];

    const int tid  = threadIdx.x;
    const int ot   = blockIdx.x / 288;
    const int pt   = blockIdx.x % 288;
    const int pos0 = pt * 128;
    const int b    = pos0 / HW;
    const int posr = pos0 - b * HW;

    const float* offp = off + (size_t)b * OFFC * HW;
    for (int s = tid; s < 9 * 128; s += 256) {
        int tt = s >> 7, j = s & 127;
        int pr = posr + j;
        float dy = offp[(2 * tt) * HW + pr];
        float dx = offp[(2 * tt + 1) * HW + pr];
        meta[tt][j] = make_meta(pr, tt, dy, dx);
    }
    __syncthreads();

    const int l15 = tid & 15;
    const int l4  = (tid >> 4) & 3;
    const int wav = tid >> 6;
    const int wp  = wav >> 1, wwo = wav & 1;
    const int j     = tid & 127;
    const int khalf = tid >> 7;
    const int wo_o  = tid >> 4;
    const int wk    = (tid & 15) * 4;

    const float* wbase = w_dc + (size_t)(ot * 128) * KDIM;

    f32x4 acc[4][4];
    #pragma unroll
    for (int f = 0; f < 4; ++f)
        #pragma unroll
        for (int g = 0; g < 4; ++g)
            acc[f][g] = (f32x4){0.f, 0.f, 0.f, 0.f};

    for (int k0 = 0; k0 < KDIM; k0 += 64) {
        #pragma unroll
        for (int r = 0; r < 8; ++r) {
            int o = r * 16 + wo_o;
            const float4 wv = *(const float4*)(wbase + (size_t)o * KDIM + k0 + wk);
            uint2 u;
            u.x = pack2(wv.x, wv.y);
            u.y = pack2(wv.z, wv.w);
            *(uint2*)(WlB + o * 128 + ((wk * 2) ^ ((o & 7) << 4))) = u;
        }
        {
            unsigned kb = (unsigned)(k0 + khalf * 32);
            unsigned c  = kb / 9u;
            unsigned tt = kb - c * 9u;
            const float* xc = x + (size_t)((unsigned)b * CC + c) * HW;
            char* vrow = VlB + j * 128;
            const unsigned swz = (unsigned)((j & 7) << 4);
            #pragma unroll
            for (int g = 0; g < 4; ++g) {
                float v[8];
                #pragma unroll
                for (int e = 0; e < 8; ++e) {
                    uint4 m = meta[tt][j];
                    float A0 = xc[m.x], A1 = xc[m.x + 1];
                    float B0 = xc[m.y], B1 = xc[m.y + 1];
                    float a0 = __uint_as_float(m.z << 16);
                    float a1 = __uint_as_float(m.z & 0xffff0000u);
                    float b0 = __uint_as_float(m.w << 16);
                    float b1 = __uint_as_float(m.w & 0xffff0000u);
                    v[e] = fmaf(a0, A0, fmaf(a1, A1, fmaf(b0, B0, b1 * B1)));
                    ++tt;
                    if (tt == 9u) { tt = 0u; xc += HW; }
                }
                uint4 pk;
                pk.x = pack2(v[0], v[1]); pk.y = pack2(v[2], v[3]);
                pk.z = pack2(v[4], v[5]); pk.w = pack2(v[6], v[7]);
                *(uint4*)(vrow + (((unsigned)(khalf * 64 + g * 16)) ^ swz)) = pk;
            }
        }
        __syncthreads();

        #pragma unroll
        for (int ks = 0; ks < 2; ++ks) {
            bf16x8 a[4], bw[4];
            #pragma unroll
            for (int f = 0; f < 4; ++f) {
                int p_loc = wp * 64 + f * 16 + l15;
                a[f] = *(const bf16x8*)(VlB + p_loc * 128 +
                                        ((ks * 64 + l4 * 16) ^ ((p_loc & 7) << 4)));
            }
            #pragma unroll
            for (int g = 0; g < 4; ++g) {
                int o_loc = wwo * 64 + g * 16 + l15;
                bw[g] = *(const bf16x8*)(WlB + o_loc * 128 +
                                         ((ks * 64 + l4 * 16) ^ ((o_loc & 7) << 4)));
            }
            #pragma unroll
            for (int f = 0; f < 4; ++f)
                #pragma unroll
                for (int g = 0; g < 4; ++g)
                    acc[f][g] = __builtin_amdgcn_mfma_f32_16x16x32_bf16(a[f], bw[g], acc[f][g], 0, 0, 0);
        }
        __syncthreads();
    }

    #pragma unroll
    for (int g = 0; g < 4; ++g) {
        int og = ot * 128 + wwo * 64 + g * 16 + l15;
        float bias = b_dc[og];
        float* op = out + ((size_t)b * OO + og) * HW + posr + wp * 64 + l4 * 4;
        #pragma unroll
        for (int f = 0; f < 4; ++f) {
            f32x4 r = acc[f][g];
            float4 st;
            st.x = r[0] + bias; st.y = r[1] + bias;
            st.z = r[2] + bias; st.w = r[3] + bias;
            *(float4*)(op + f * 16) = st;
        }
    }
}

extern "C" void kernel_launch(void* const* d_in, const int* in_sizes, int n_in,
                              void* d_out, int out_size, void* d_ws, size_t ws_size,
                              hipStream_t stream)
{
    const float* x     = (const float*)d_in[0];
    const float* w_off = (const float*)d_in[1];
    const float* b_off = (const float*)d_in[2];
    const float* w_dc  = (const float*)d_in[3];
    const float* b_dc  = (const float*)d_in[4];
    float* out = (float*)d_out;

    if (ws_size >= WS_NEED) {
        char*  ws   = (char*)d_ws;
        char*  Vg   = ws;
        char*  Wb   = ws + WS_WB_OFF;
        uint4* meta = (uint4*)(ws + WS_META_OFF);
        offset_meta_kernel<<<BB * 144, 256, 0, stream>>>(x, w_off, b_off, meta);
        wconv_kernel<<<288, 256, 0, stream>>>(w_dc, Wb);
        gather_kernel7<<<288 * NKC, 256, 0, stream>>>(x, meta, Vg);
        gemm_kernel<<<576, 256, 0, stream>>>(Vg, Wb, b_dc, out);
    } else {
        float* off = (float*)d_ws;
        offset_conv6_kernel<<<BB * 36 * 3, 256, 0, stream>>>(x, w_off, b_off, off);
        deform_mfma_kernel<<<(OO / 128) * (BB * HW / 128), 256, 0, stream>>>(x, off, w_dc, b_dc, out);
    }
}

// Round 11
// 312.456 us; speedup vs baseline: 1.2787x; 1.2787x over previous
//
#include <hip/hip_runtime.h>
#include <hip/hip_fp16.h>
#include <math.h>

#define BB   4
#define CC   256
#define HH   96
#define WW   96
#define OO   256
#define HW   9216        // HH*WW
#define KDIM 2304        // CC*9
#define OFFC 18
#define NKC  36          // K chunks of 64

// K ordering (split path): k' = tap*256 + c (tap-major). V, Wb, offset_meta
// staging all use k'; GEMM is ordering-agnostic.
// V-row content swizzle: 16B unit at byte g16*16 is XOR'd by ((p&1)<<4)
// (1-bit: gather writes 32B-granular units; GEMM A-read matches).

typedef short bf16x8 __attribute__((ext_vector_type(8)));
typedef float f32x4  __attribute__((ext_vector_type(4)));
typedef unsigned int u32x4 __attribute__((ext_vector_type(4)));

// ---- ws layout (split path) ----
#define WS_V_SZ    (36864ull * 4608ull)               // V bf16 [p][k'], row 4608B
#define WS_WB_OFF  WS_V_SZ
#define WS_WB_SZ   (256ull * 4608ull)                 // W bf16 [o][k'], pre-swizzled
#define WS_META_OFF (WS_WB_OFF + WS_WB_SZ)
#define WS_META_SZ (4ull * 9ull * 9216ull * 16ull)    // region (meta2 uses 1/4)
#define WS_NEED    (WS_META_OFF + WS_META_SZ)         // ~176.4 MB

__device__ __forceinline__ unsigned short f2bfu(float f) {
    unsigned u = __float_as_uint(f);
    unsigned r = (u + 0x7fffu + ((u >> 16) & 1u)) >> 16;   // RNE
    return (unsigned short)r;
}
__device__ __forceinline__ unsigned pack2(float lo, float hi) {
    return (unsigned)f2bfu(lo) | ((unsigned)f2bfu(hi) << 16);
}
__device__ __forceinline__ void gload16(const void* g, void* l) {
    __builtin_amdgcn_global_load_lds((const __attribute__((address_space(1))) void*)g,
                                     (__attribute__((address_space(3))) void*)l, 16, 0, 0);
}

__device__ __forceinline__ uint4 make_meta(int pr, int t, float dy, float dx) {
    int oh = pr / WW, ow = pr - oh * WW;
    float py = (float)(oh - 1 + t / 3) + dy;
    float px = (float)(ow - 1 + (t % 3)) + dx;
    float y0f = floorf(py), x0f = floorf(px);
    int y0 = (int)y0f, x0 = (int)x0f;
    float ly = py - y0f, lx = px - x0f;
    float wy0 = (y0 >= 0 && y0 < HH) ? 1.f - ly : 0.f;
    float wy1 = (y0 + 1 >= 0 && y0 + 1 < HH) ? ly : 0.f;
    float u0 = (x0 >= 0 && x0 < WW) ? 1.f - lx : 0.f;
    float u1 = (x0 + 1 >= 0 && x0 + 1 < WW) ? lx : 0.f;
    int pb = min(max(x0, 0), WW - 2);
    float s0, s1;
    if (x0 < 0)           { s0 = u1; s1 = 0.f; }
    else if (x0 > WW - 2) { s0 = 0.f; s1 = u0; }
    else                  { s0 = u0; s1 = u1; }
    int cy0 = min(max(y0, 0), HH - 1);
    int cy1 = min(max(y0 + 1, 0), HH - 1);
    uint4 m;
    m.x = (unsigned)(cy0 * WW + pb);
    m.y = (unsigned)(cy1 * WW + pb);
    m.z = pack2(wy0 * s0, wy0 * s1);
    m.w = pack2(wy1 * s0, wy1 * s1);
    return m;
}

// ================= SPLIT PATH =================

// ---- Kernel A: offset conv via MFMA (64p x 32oc tile) -> compact fp16 (dy,dx) ----
__global__ __launch_bounds__(256)
void offset_meta_kernel(const float* __restrict__ x,
                        const float* __restrict__ w_off,
                        const float* __restrict__ b_off,
                        unsigned* __restrict__ meta2_ws)
{
    __shared__ __align__(16) char Asw[64 * 128];
    __shared__ __align__(16) char Wl[32 * 128];
    __shared__ float Dsh[64][21];

    const int tid = threadIdx.x;
    const int fin = ((blockIdx.x & 7) * 72) + (blockIdx.x >> 3);  // XCD-chunked (576 = 8*72)
    const int b   = fin / 144;
    const int pr0 = (fin % 144) * 64;
    const float* xb = x + (size_t)b * CC * HW;

    const int l15 = tid & 15;
    const int l4  = (tid >> 4) & 3;
    const int wav = tid >> 6;
    const int sp  = tid & 63;       // A staging: p row
    const int kq  = tid >> 6;       // A staging: c quarter (16 c)
    const int so  = tid >> 3;       // W staging: o row 0..31
    const int sq  = tid & 7;        // W staging: q group (8 c)

    const int prg = pr0 + sp;
    const int oh = prg / WW, ow = prg - (prg / WW) * WW;

    f32x4 acc[2];
    acc[0] = (f32x4){0.f, 0.f, 0.f, 0.f};
    acc[1] = (f32x4){0.f, 0.f, 0.f, 0.f};

    for (int kc = 0; kc < NKC; ++kc) {
        const int tap = kc >> 2;
        const int cb  = (kc & 3) * 64;
        {
            uint4 pk;
            if (so < OFFC) {
                const float* wr = w_off + (size_t)so * KDIM + (cb + sq * 8) * 9 + tap;
                float wv[8];
                #pragma unroll
                for (int i = 0; i < 8; ++i) wv[i] = wr[i * 9];
                pk.x = pack2(wv[0], wv[1]); pk.y = pack2(wv[2], wv[3]);
                pk.z = pack2(wv[4], wv[5]); pk.w = pack2(wv[6], wv[7]);
            } else { pk.x = pk.y = pk.z = pk.w = 0u; }
            *(uint4*)(Wl + so * 128 + ((sq * 16) ^ ((so & 7) << 4))) = pk;
        }
        {
            int iy = oh + tap / 3 - 1;
            int ix = ow + tap % 3 - 1;
            bool ok = (iy >= 0) & (iy < HH) & (ix >= 0) & (ix < WW);
            const float* xp = xb + (size_t)(cb + kq * 16) * HW + iy * WW + ix;
            float v[16];
            #pragma unroll
            for (int e = 0; e < 16; ++e)
                v[e] = ok ? xp[(size_t)e * HW] : 0.f;
            char* arow = Asw + sp * 128;
            unsigned swz = (unsigned)((sp & 7) << 4);
            uint4 p0, p1;
            p0.x = pack2(v[0], v[1]);   p0.y = pack2(v[2], v[3]);
            p0.z = pack2(v[4], v[5]);   p0.w = pack2(v[6], v[7]);
            p1.x = pack2(v[8], v[9]);   p1.y = pack2(v[10], v[11]);
            p1.z = pack2(v[12], v[13]); p1.w = pack2(v[14], v[15]);
            *(uint4*)(arow + (((unsigned)(kq * 32 + 0)) ^ swz)) = p0;
            *(uint4*)(arow + (((unsigned)(kq * 32 + 16)) ^ swz)) = p1;
        }
        __syncthreads();
        {
            int p_loc = wav * 16 + l15;
            unsigned aswz = (unsigned)((p_loc & 7) << 4);
            #pragma unroll
            for (int ks = 0; ks < 2; ++ks) {
                bf16x8 a = *(const bf16x8*)(Asw + p_loc * 128 + ((ks * 64 + l4 * 16) ^ aswz));
                #pragma unroll
                for (int g = 0; g < 2; ++g) {
                    int o_loc = g * 16 + l15;
                    bf16x8 bw = *(const bf16x8*)(Wl + o_loc * 128 +
                                                 ((ks * 64 + l4 * 16) ^ ((o_loc & 7) << 4)));
                    acc[g] = __builtin_amdgcn_mfma_f32_16x16x32_bf16(a, bw, acc[g], 0, 0, 0);
                }
            }
        }
        __syncthreads();
    }

    #pragma unroll
    for (int g = 0; g < 2; ++g) {
        int o = g * 16 + l15;
        if (o < OFFC) {
            float bo = b_off[o];
            #pragma unroll
            for (int r = 0; r < 4; ++r)
                Dsh[wav * 16 + l4 * 4 + r][o] = acc[g][r] + bo;
        }
    }
    __syncthreads();
    // emit compact (dy,dx) as 2xfp16 per (tap, p)
    for (int s = tid; s < 9 * 64; s += 256) {
        int t = s >> 6, pl = s & 63;
        int pr = pr0 + pl;
        float dy = Dsh[pl][2 * t];
        float dx = Dsh[pl][2 * t + 1];
        unsigned lo = (unsigned)__half_as_ushort(__float2half(dy));
        unsigned hi = (unsigned)__half_as_ushort(__float2half(dx));
        meta2_ws[((size_t)b * 9 + t) * HW + pr] = lo | (hi << 16);
    }
}

// ---- Kernel B: w_dc fp32 -> bf16 pre-swizzled, k' = tap*256 + c (B keeps 3-bit swz) ----
__global__ __launch_bounds__(256)
void wconv_kernel(const float* __restrict__ w_dc, char* __restrict__ wb)
{
    int idx = blockIdx.x * 256 + (int)threadIdx.x;   // 73728
    int o   = idx / 288;
    int rem = idx - o * 288;
    int ch  = rem >> 3;          // chunk 0..35
    int q   = rem & 7;           // q group
    int tap = ch >> 2;
    int c0  = (ch & 3) * 64 + q * 8;
    const float* wr = w_dc + (size_t)o * KDIM + (size_t)c0 * 9 + tap;
    float wv[8];
    #pragma unroll
    for (int i = 0; i < 8; ++i) wv[i] = wr[i * 9];
    uint4 pk;
    pk.x = pack2(wv[0], wv[1]); pk.y = pack2(wv[2], wv[3]);
    pk.z = pack2(wv[4], wv[5]); pk.w = pack2(wv[6], wv[7]);
    *(uint4*)(wb + (size_t)o * 4608 + ch * 128 + ((q * 16) ^ ((o & 7) << 4))) = pk;
}

// ---- Kernel C: 9-tap row-shared bilinear gather ----
// block = (6-image-row tile [576p], 16-channel group). Stage 14 x-rows/ch in
// LDS once; ALL 9 taps read from LDS (12x line-traffic reduction). Per-lane
// guard falls back to exact global loads when |dy| pushes corners outside the
// staged window (~3e-5 of elements). Output: register-direct 16B stores,
// 32B-granular units, V-row swizzle = ((p&1)<<4).
#define GT_P   576
#define GT_WIN 14
__global__ __launch_bounds__(512)
void gather_kernel8(const float* __restrict__ x,
                    const unsigned* __restrict__ meta2,
                    char* __restrict__ Vg)
{
    __shared__ float Xs[16 * GT_WIN * 100];   // [ch][row][100] fp32, 87.5KB
    __shared__ unsigned Md[9 * GT_P];         // fp16x2 per (tap,p), 20.25KB

    int bid  = blockIdx.x;                    // 1024 = 8 * 128
    int fin  = (bid & 7) * 128 + (bid >> 3);  // XCD-chunked
    int tile = fin >> 4;                      // 0..63 (b*16 + trow)
    int cq   = fin & 15;                      // 0..15 (16ch each)
    int b    = tile >> 4;
    int h0   = (tile & 15) * 6;
    int c0   = cq * 16;
    int tid  = threadIdx.x;
    int prow0 = tile * GT_P;

    int r0 = h0 - 3; r0 = r0 < 0 ? 0 : (r0 > 82 ? 82 : r0);   // staged rows [r0, r0+13]

    for (int s = tid; s < 9 * GT_P; s += 512) {
        int t = s / GT_P, pl = s - t * GT_P;
        Md[s] = meta2[((size_t)b * 9 + t) * HW + h0 * WW + pl];
    }

    // stage 16ch x 14 rows x 96 cols (float4 units; rows all in [0,95])
    const float* xb = x + ((size_t)b * CC + c0) * HW + r0 * WW;
    for (int u = tid; u < 16 * GT_WIN * 24; u += 512) {
        int ch  = u / (GT_WIN * 24);
        int rem = u - ch * (GT_WIN * 24);
        int row = rem / 24, un = rem - row * 24;
        float4 v = *(const float4*)(xb + (size_t)ch * HW + row * WW + un * 4);
        *(float4*)(&Xs[(ch * GT_WIN + row) * 100 + un * 4]) = v;
    }
    __syncthreads();

    const int chh  = tid & 1;                 // 8-ch slot
    const int lsub = (tid & 63) >> 1;         // 0..31 positions per wave
    const int w    = tid >> 6;                // wave 0..7
    const float* xg = x + ((size_t)b * CC + c0 + chh * 8) * HW;  // slow-path base
    const float* xsb = &Xs[(chh * 8) * GT_WIN * 100];

    for (int pass = 0; pass < 3; ++pass) {
        int i = pass * 256 + w * 32 + lsub;   // wave-uniform in/out of range
        if (i >= GT_P) break;
        int oh = h0 + i / WW, ow = i - (i / WW) * WW;
        char* vrow = Vg + (size_t)(prow0 + i) * 4608 + cq * 32 +
                     ((chh * 16) ^ ((i & 1) << 4));
        #pragma unroll
        for (int t = 0; t < 9; ++t) {
            unsigned md = Md[t * GT_P + i];
            float dy = __half2float(__ushort_as_half((unsigned short)(md & 0xffffu)));
            float dx = __half2float(__ushort_as_half((unsigned short)(md >> 16)));
            float py = (float)(oh - 1 + t / 3) + dy;
            float px = (float)(ow - 1 + t % 3) + dx;
            float y0f = floorf(py), x0f = floorf(px);
            int y0 = (int)y0f, x0 = (int)x0f;
            float ly = py - y0f, lx = px - x0f;
            float wy0 = (y0 >= 0 && y0 < HH) ? 1.f - ly : 0.f;
            float wy1 = (y0 + 1 >= 0 && y0 + 1 < HH) ? ly : 0.f;
            float u0 = (x0 >= 0 && x0 < WW) ? 1.f - lx : 0.f;
            float u1 = (x0 + 1 >= 0 && x0 + 1 < WW) ? lx : 0.f;
            int pb = min(max(x0, 0), WW - 2);
            float s0, s1;
            if (x0 < 0)           { s0 = u1; s1 = 0.f; }
            else if (x0 > WW - 2) { s0 = 0.f; s1 = u0; }
            else                  { s0 = u0; s1 = u1; }
            int cy0 = min(max(y0, 0), HH - 1);
            int cy1 = min(max(y0 + 1, 0), HH - 1);
            float wa0 = wy0 * s0, wa1 = wy0 * s1;
            float wb0 = wy1 * s0, wb1 = wy1 * s1;
            float v[8];
            if (cy0 >= r0 && cy1 <= r0 + GT_WIN - 1) {
                const float* ra = xsb + (size_t)(cy0 - r0) * 100 + pb;
                const float* rb = xsb + (size_t)(cy1 - r0) * 100 + pb;
                #pragma unroll
                for (int k = 0; k < 8; ++k) {
                    float A0 = ra[k * GT_WIN * 100], A1 = ra[k * GT_WIN * 100 + 1];
                    float B0 = rb[k * GT_WIN * 100], B1 = rb[k * GT_WIN * 100 + 1];
                    v[k] = fmaf(wa0, A0, fmaf(wa1, A1, fmaf(wb0, B0, wb1 * B1)));
                }
            } else {                                   // rare exact fallback
                const float* pa = xg + cy0 * WW + pb;
                const float* pq = xg + cy1 * WW + pb;
                #pragma unroll
                for (int k = 0; k < 8; ++k) {
                    float A0 = pa[(size_t)k * HW], A1 = pa[(size_t)k * HW + 1];
                    float B0 = pq[(size_t)k * HW], B1 = pq[(size_t)k * HW + 1];
                    v[k] = fmaf(wa0, A0, fmaf(wa1, A1, fmaf(wb0, B0, wb1 * B1)));
                }
            }
            u32x4 pk;
            pk.x = pack2(v[0], v[1]); pk.y = pack2(v[2], v[3]);
            pk.z = pack2(v[4], v[5]); pk.w = pack2(v[6], v[7]);
            *(u32x4*)(vrow + t * 512) = pk;
        }
    }
}

// ---- Kernel D: streaming GEMM, 2-phase double-buffered, global_load_lds ----
// A-fragment de-swizzle = ((p&1)<<4) to match gather8's 32B-granular writes.
__global__ __launch_bounds__(256)
void gemm_kernel(const char* __restrict__ Vg, const char* __restrict__ Wb,
                 const float* __restrict__ b_dc, float* __restrict__ out)
{
    __shared__ __align__(16) char Ab[2][128 * 128];
    __shared__ __align__(16) char Bb[2][128 * 128];

    int bid = blockIdx.x;
    int swzb = (bid & 7) * 72 + (bid >> 3);   // both ot of a pt share an XCD
    int pt = swzb >> 1, ot = swzb & 1;
    int tid = threadIdx.x;
    int lane = tid & 63, wav = tid >> 6;
    const int l15 = tid & 15, l4 = (tid >> 4) & 3;
    const int wp = wav >> 1, wo = wav & 1;

    const char* Ag = Vg + (size_t)(pt * 128) * 4608;
    const char* Bg = Wb + (size_t)(ot * 128) * 4608;
    const int rsub = lane >> 3;
    const int csub = (lane & 7) * 16;

    f32x4 acc[4][4];
    #pragma unroll
    for (int f = 0; f < 4; ++f)
        #pragma unroll
        for (int g = 0; g < 4; ++g)
            acc[f][g] = (f32x4){0.f, 0.f, 0.f, 0.f};

#define STAGE(bufi, t) {                                                        \
        const char* ag = Ag + (size_t)(t) * 128;                                \
        const char* bg = Bg + (size_t)(t) * 128;                                \
        _Pragma("unroll")                                                       \
        for (int i = 0; i < 4; ++i) {                                           \
            int r0 = wav * 32 + i * 8;                                          \
            gload16(ag + (size_t)(r0 + rsub) * 4608 + csub, &Ab[bufi][r0 * 128]);\
            gload16(bg + (size_t)(r0 + rsub) * 4608 + csub, &Bb[bufi][r0 * 128]);\
        } }

    STAGE(0, 0);
    __syncthreads();

    int cur = 0;
    for (int t = 0; t < NKC; ++t) {
        if (t + 1 < NKC) STAGE(cur ^ 1, t + 1);
        #pragma unroll
        for (int ks = 0; ks < 2; ++ks) {
            bf16x8 a[4], bw[4];
            #pragma unroll
            for (int f = 0; f < 4; ++f) {
                int p_loc = wp * 64 + f * 16 + l15;
                a[f] = *(const bf16x8*)(Ab[cur] + p_loc * 128 +
                                        ((ks * 64 + l4 * 16) ^ ((p_loc & 1) << 4)));
            }
            #pragma unroll
            for (int g = 0; g < 4; ++g) {
                int o_loc = wo * 64 + g * 16 + l15;
                bw[g] = *(const bf16x8*)(Bb[cur] + o_loc * 128 +
                                         ((ks * 64 + l4 * 16) ^ ((o_loc & 7) << 4)));
            }
            #pragma unroll
            for (int f = 0; f < 4; ++f)
                #pragma unroll
                for (int g = 0; g < 4; ++g)
                    acc[f][g] = __builtin_amdgcn_mfma_f32_16x16x32_bf16(a[f], bw[g], acc[f][g], 0, 0, 0);
        }
        __syncthreads();
        cur ^= 1;
    }

    int b = pt / 72;
    int posr = (pt - b * 72) * 128;
    #pragma unroll
    for (int g = 0; g < 4; ++g) {
        int og = ot * 128 + wo * 64 + g * 16 + l15;
        float bias = b_dc[og];
        float* op = out + ((size_t)b * OO + og) * HW + posr + wp * 64 + l4 * 4;
        #pragma unroll
        for (int f = 0; f < 4; ++f) {
            f32x4 r = acc[f][g];
            float4 st;
            st.x = r[0] + bias; st.y = r[1] + bias;
            st.z = r[2] + bias; st.w = r[3] + bias;
            *(float4*)(op + f * 16) = st;
        }
    }
}

// ================= FALLBACK PATH (round-2, verified) =================

__global__ __launch_bounds__(256)
void offset_conv6_kernel(const float* __restrict__ x,
                         const float* __restrict__ w_off,
                         const float* __restrict__ b_off,
                         float* __restrict__ off)
{
    int bid   = blockIdx.x;
    int g     = bid % 3;
    int chunk = (bid / 3) % 36;
    int b     = bid / 108;
    int ocb   = g * 6;
    int pr    = chunk * 256 + (int)threadIdx.x;
    int oh    = pr / WW, ow = pr % WW;
    const float* xb = x + (size_t)b * CC * HW;

    float acc[6];
    #pragma unroll
    for (int i = 0; i < 6; ++i) acc[i] = b_off[ocb + i];

    bool interior = (oh >= 1) & (oh < HH - 1) & (ow >= 1) & (ow < WW - 1);
    if (interior) {
        const float* xp = xb + (oh - 1) * WW + (ow - 1);
        float xv[9];
        #pragma unroll
        for (int t = 0; t < 9; ++t) xv[t] = xp[(t / 3) * WW + (t % 3)];
        for (int c = 0; c < CC; ++c) {
            float xn[9];
            if (c + 1 < CC) {
                const float* xq = xp + (size_t)(c + 1) * HW;
                #pragma unroll
                for (int t = 0; t < 9; ++t) xn[t] = xq[(t / 3) * WW + (t % 3)];
            }
            #pragma unroll
            for (int i = 0; i < 6; ++i) {
                const float* wr = w_off + ((size_t)(ocb + i) * CC + c) * 9;
                #pragma unroll
                for (int t = 0; t < 9; ++t)
                    acc[i] = fmaf(xv[t], wr[t], acc[i]);
            }
            #pragma unroll
            for (int t = 0; t < 9; ++t) xv[t] = xn[t];
        }
    } else {
        for (int c = 0; c < CC; ++c) {
            const float* xc = xb + (size_t)c * HW;
            float xv[9];
            #pragma unroll
            for (int t = 0; t < 9; ++t) {
                int yy = oh + t / 3 - 1, xx = ow + t % 3 - 1;
                xv[t] = (yy >= 0 && yy < HH && xx >= 0 && xx < WW) ? xc[yy * WW + xx] : 0.f;
            }
            #pragma unroll
            for (int i = 0; i < 6; ++i) {
                const float* wr = w_off + ((size_t)(ocb + i) * CC + c) * 9;
                #pragma unroll
                for (int t = 0; t < 9; ++t)
                    acc[i] = fmaf(xv[t], wr[t], acc[i]);
            }
        }
    }
    #pragma unroll
    for (int i = 0; i < 6; ++i)
        off[((size_t)b * OFFC + ocb + i) * HW + pr] = acc[i];
}

__global__ __launch_bounds__(256)
void deform_mfma_kernel(const float* __restrict__ x,
                        const float* __restrict__ off,
                        const float* __restrict__ w_dc,
                        const float* __restrict__ b_dc,
                        float* __restrict__ out)
{
    __shared__ __align__(16) char VlB[128 * 128];
    __shared__ __align__(16) char WlB[128 * 128];
    __shared__ uint4 meta[9][128];

    const int tid  = threadIdx.x;
    const int ot   = blockIdx.x / 288;
    const int pt   = blockIdx.x % 288;
    const int pos0 = pt * 128;
    const int b    = pos0 / HW;
    const int posr = pos0 - b * HW;

    const float* offp = off + (size_t)b * OFFC * HW;
    for (int s = tid; s < 9 * 128; s += 256) {
        int tt = s >> 7, j = s & 127;
        int pr = posr + j;
        float dy = offp[(2 * tt) * HW + pr];
        float dx = offp[(2 * tt + 1) * HW + pr];
        meta[tt][j] = make_meta(pr, tt, dy, dx);
    }
    __syncthreads();

    const int l15 = tid & 15;
    const int l4  = (tid >> 4) & 3;
    const int wav = tid >> 6;
    const int wp  = wav >> 1, wwo = wav & 1;
    const int j     = tid & 127;
    const int khalf = tid >> 7;
    const int wo_o  = tid >> 4;
    const int wk    = (tid & 15) * 4;

    const float* wbase = w_dc + (size_t)(ot * 128) * KDIM;

    f32x4 acc[4][4];
    #pragma unroll
    for (int f = 0; f < 4; ++f)
        #pragma unroll
        for (int g = 0; g < 4; ++g)
            acc[f][g] = (f32x4){0.f, 0.f, 0.f, 0.f};

    for (int k0 = 0; k0 < KDIM; k0 += 64) {
        #pragma unroll
        for (int r = 0; r < 8; ++r) {
            int o = r * 16 + wo_o;
            const float4 wv = *(const float4*)(wbase + (size_t)o * KDIM + k0 + wk);
            uint2 u;
            u.x = pack2(wv.x, wv.y);
            u.y = pack2(wv.z, wv.w);
            *(uint2*)(WlB + o * 128 + ((wk * 2) ^ ((o & 7) << 4))) = u;
        }
        {
            unsigned kb = (unsigned)(k0 + khalf * 32);
            unsigned c  = kb / 9u;
            unsigned tt = kb - c * 9u;
            const float* xc = x + (size_t)((unsigned)b * CC + c) * HW;
            char* vrow = VlB + j * 128;
            const unsigned swz = (unsigned)((j & 7) << 4);
            #pragma unroll
            for (int g = 0; g < 4; ++g) {
                float v[8];
                #pragma unroll
                for (int e = 0; e < 8; ++e) {
                    uint4 m = meta[tt][j];
                    float A0 = xc[m.x], A1 = xc[m.x + 1];
                    float B0 = xc[m.y], B1 = xc[m.y + 1];
                    float a0 = __uint_as_float(m.z << 16);
                    float a1 = __uint_as_float(m.z & 0xffff0000u);
                    float b0 = __uint_as_float(m.w << 16);
                    float b1 = __uint_as_float(m.w & 0xffff0000u);
                    v[e] = fmaf(a0, A0, fmaf(a1, A1, fmaf(b0, B0, b1 * B1)));
                    ++tt;
                    if (tt == 9u) { tt = 0u; xc += HW; }
                }
                uint4 pk;
                pk.x = pack2(v[0], v[1]); pk.y = pack2(v[2], v[3]);
                pk.z = pack2(v[4], v[5]); pk.w = pack2(v[6], v[7]);
                *(uint4*)(vrow + (((unsigned)(khalf * 64 + g * 16)) ^ swz)) = pk;
            }
        }
        __syncthreads();

        #pragma unroll
        for (int ks = 0; ks < 2; ++ks) {
            bf16x8 a[4], bw[4];
            #pragma unroll
            for (int f = 0; f < 4; ++f) {
                int p_loc = wp * 64 + f * 16 + l15;
                a[f] = *(const bf16x8*)(VlB + p_loc * 128 +
                                        ((ks * 64 + l4 * 16) ^ ((p_loc & 7) << 4)));
            }
            #pragma unroll
            for (int g = 0; g < 4; ++g) {
                int o_loc = wwo * 64 + g * 16 + l15;
                bw[g] = *(const bf16x8*)(WlB + o_loc * 128 +
                                         ((ks * 64 + l4 * 16) ^ ((o_loc & 7) << 4)));
            }
            #pragma unroll
            for (int f = 0; f < 4; ++f)
                #pragma unroll
                for (int g = 0; g < 4; ++g)
                    acc[f][g] = __builtin_amdgcn_mfma_f32_16x16x32_bf16(a[f], bw[g], acc[f][g], 0, 0, 0);
        }
        __syncthreads();
    }

    #pragma unroll
    for (int g = 0; g < 4; ++g) {
        int og = ot * 128 + wwo * 64 + g * 16 + l15;
        float bias = b_dc[og];
        float* op = out + ((size_t)b * OO + og) * HW + posr + wp * 64 + l4 * 4;
        #pragma unroll
        for (int f = 0; f < 4; ++f) {
            f32x4 r = acc[f][g];
            float4 st;
            st.x = r[0] + bias; st.y = r[1] + bias;
            st.z = r[2] + bias; st.w = r[3] + bias;
            *(float4*)(op + f * 16) = st;
        }
    }
}

extern "C" void kernel_launch(void* const* d_in, const int* in_sizes, int n_in,
                              void* d_out, int out_size, void* d_ws, size_t ws_size,
                              hipStream_t stream)
{
    const float* x     = (const float*)d_in[0];
    const float* w_off = (const float*)d_in[1];
    const float* b_off = (const float*)d_in[2];
    const float* w_dc  = (const float*)d_in[3];
    const float* b_dc  = (const float*)d_in[4];
    float* out = (float*)d_out;

    if (ws_size >= WS_NEED) {
        char*     ws    = (char*)d_ws;
        char*     Vg    = ws;
        char*     Wb    = ws + WS_WB_OFF;
        unsigned* meta2 = (unsigned*)(ws + WS_META_OFF);
        offset_meta_kernel<<<BB * 144, 256, 0, stream>>>(x, w_off, b_off, meta2);
        wconv_kernel<<<288, 256, 0, stream>>>(w_dc, Wb);
        gather_kernel8<<<1024, 512, 0, stream>>>(x, meta2, Vg);
        gemm_kernel<<<576, 256, 0, stream>>>(Vg, Wb, b_dc, out);
    } else {
        float* off = (float*)d_ws;
        offset_conv6_kernel<<<BB * 36 * 3, 256, 0, stream>>>(x, w_off, b_off, off);
        deform_mfma_kernel<<<(OO / 128) * (BB * HW / 128), 256, 0, stream>>>(x, off, w_dc, b_dc, out);
    }
}

// Round 12
// 251.176 us; speedup vs baseline: 1.5906x; 1.2440x over previous
//
#include <hip/hip_runtime.h>
#include <hip/hip_fp16.h>
#include <math.h>

#define BB   4
#define CC   256
#define HH   96
#define WW   96
#define OO   256
#define HW   9216        // HH*WW
#define KDIM 2304        // CC*9
#define OFFC 18
#define NKC  36          // K chunks of 64

// K ordering (split path): k' = tap*256 + c (tap-major).
// V-row content swizzle: 16B unit XOR'd by ((p&1)<<4); GEMM A-read matches.

typedef short bf16x8 __attribute__((ext_vector_type(8)));
typedef float f32x4  __attribute__((ext_vector_type(4)));
typedef unsigned int u32x4 __attribute__((ext_vector_type(4)));

// ---- ws layout (split path) ----
#define WS_V_SZ    (36864ull * 4608ull)               // V bf16 [p][k'], row 4608B
#define WS_WB_OFF  WS_V_SZ
#define WS_WB_SZ   (256ull * 4608ull)                 // W bf16 [o][k'], pre-swizzled
#define WS_META_OFF (WS_WB_OFF + WS_WB_SZ)
#define WS_META_SZ (4ull * 9ull * 9216ull * 16ull)    // region (meta2 uses 1/4)
#define WS_NEED    (WS_META_OFF + WS_META_SZ)         // ~176.4 MB

__device__ __forceinline__ unsigned short f2bfu(float f) {
    unsigned u = __float_as_uint(f);
    unsigned r = (u + 0x7fffu + ((u >> 16) & 1u)) >> 16;   // RNE
    return (unsigned short)r;
}
__device__ __forceinline__ unsigned pack2(float lo, float hi) {
    return (unsigned)f2bfu(lo) | ((unsigned)f2bfu(hi) << 16);
}
__device__ __forceinline__ void gload16(const void* g, void* l) {
    __builtin_amdgcn_global_load_lds((const __attribute__((address_space(1))) void*)g,
                                     (__attribute__((address_space(3))) void*)l, 16, 0, 0);
}

__device__ __forceinline__ uint4 make_meta(int pr, int t, float dy, float dx) {
    int oh = pr / WW, ow = pr - oh * WW;
    float py = (float)(oh - 1 + t / 3) + dy;
    float px = (float)(ow - 1 + (t % 3)) + dx;
    float y0f = floorf(py), x0f = floorf(px);
    int y0 = (int)y0f, x0 = (int)x0f;
    float ly = py - y0f, lx = px - x0f;
    float wy0 = (y0 >= 0 && y0 < HH) ? 1.f - ly : 0.f;
    float wy1 = (y0 + 1 >= 0 && y0 + 1 < HH) ? ly : 0.f;
    float u0 = (x0 >= 0 && x0 < WW) ? 1.f - lx : 0.f;
    float u1 = (x0 + 1 >= 0 && x0 + 1 < WW) ? lx : 0.f;
    int pb = min(max(x0, 0), WW - 2);
    float s0, s1;
    if (x0 < 0)           { s0 = u1; s1 = 0.f; }
    else if (x0 > WW - 2) { s0 = 0.f; s1 = u0; }
    else                  { s0 = u0; s1 = u1; }
    int cy0 = min(max(y0, 0), HH - 1);
    int cy1 = min(max(y0 + 1, 0), HH - 1);
    uint4 m;
    m.x = (unsigned)(cy0 * WW + pb);
    m.y = (unsigned)(cy1 * WW + pb);
    m.z = pack2(wy0 * s0, wy0 * s1);
    m.w = pack2(wy1 * s0, wy1 * s1);
    return m;
}

// ================= SPLIT PATH =================

// ---- Kernel A: offset conv via MFMA (64p x 32oc tile) -> compact fp16 (dy,dx) ----
__global__ __launch_bounds__(256)
void offset_meta_kernel(const float* __restrict__ x,
                        const float* __restrict__ w_off,
                        const float* __restrict__ b_off,
                        unsigned* __restrict__ meta2_ws)
{
    __shared__ __align__(16) char Asw[64 * 128];
    __shared__ __align__(16) char Wl[32 * 128];
    __shared__ float Dsh[64][21];

    const int tid = threadIdx.x;
    const int fin = ((blockIdx.x & 7) * 72) + (blockIdx.x >> 3);  // XCD-chunked (576 = 8*72)
    const int b   = fin / 144;
    const int pr0 = (fin % 144) * 64;
    const float* xb = x + (size_t)b * CC * HW;

    const int l15 = tid & 15;
    const int l4  = (tid >> 4) & 3;
    const int wav = tid >> 6;
    const int sp  = tid & 63;       // A staging: p row
    const int kq  = tid >> 6;       // A staging: c quarter (16 c)
    const int so  = tid >> 3;       // W staging: o row 0..31
    const int sq  = tid & 7;        // W staging: q group (8 c)

    const int prg = pr0 + sp;
    const int oh = prg / WW, ow = prg - (prg / WW) * WW;

    f32x4 acc[2];
    acc[0] = (f32x4){0.f, 0.f, 0.f, 0.f};
    acc[1] = (f32x4){0.f, 0.f, 0.f, 0.f};

    for (int kc = 0; kc < NKC; ++kc) {
        const int tap = kc >> 2;
        const int cb  = (kc & 3) * 64;
        {
            uint4 pk;
            if (so < OFFC) {
                const float* wr = w_off + (size_t)so * KDIM + (cb + sq * 8) * 9 + tap;
                float wv[8];
                #pragma unroll
                for (int i = 0; i < 8; ++i) wv[i] = wr[i * 9];
                pk.x = pack2(wv[0], wv[1]); pk.y = pack2(wv[2], wv[3]);
                pk.z = pack2(wv[4], wv[5]); pk.w = pack2(wv[6], wv[7]);
            } else { pk.x = pk.y = pk.z = pk.w = 0u; }
            *(uint4*)(Wl + so * 128 + ((sq * 16) ^ ((so & 7) << 4))) = pk;
        }
        {
            int iy = oh + tap / 3 - 1;
            int ix = ow + tap % 3 - 1;
            bool ok = (iy >= 0) & (iy < HH) & (ix >= 0) & (ix < WW);
            const float* xp = xb + (size_t)(cb + kq * 16) * HW + iy * WW + ix;
            float v[16];
            #pragma unroll
            for (int e = 0; e < 16; ++e)
                v[e] = ok ? xp[(size_t)e * HW] : 0.f;
            char* arow = Asw + sp * 128;
            unsigned swz = (unsigned)((sp & 7) << 4);
            uint4 p0, p1;
            p0.x = pack2(v[0], v[1]);   p0.y = pack2(v[2], v[3]);
            p0.z = pack2(v[4], v[5]);   p0.w = pack2(v[6], v[7]);
            p1.x = pack2(v[8], v[9]);   p1.y = pack2(v[10], v[11]);
            p1.z = pack2(v[12], v[13]); p1.w = pack2(v[14], v[15]);
            *(uint4*)(arow + (((unsigned)(kq * 32 + 0)) ^ swz)) = p0;
            *(uint4*)(arow + (((unsigned)(kq * 32 + 16)) ^ swz)) = p1;
        }
        __syncthreads();
        {
            int p_loc = wav * 16 + l15;
            unsigned aswz = (unsigned)((p_loc & 7) << 4);
            #pragma unroll
            for (int ks = 0; ks < 2; ++ks) {
                bf16x8 a = *(const bf16x8*)(Asw + p_loc * 128 + ((ks * 64 + l4 * 16) ^ aswz));
                #pragma unroll
                for (int g = 0; g < 2; ++g) {
                    int o_loc = g * 16 + l15;
                    bf16x8 bw = *(const bf16x8*)(Wl + o_loc * 128 +
                                                 ((ks * 64 + l4 * 16) ^ ((o_loc & 7) << 4)));
                    acc[g] = __builtin_amdgcn_mfma_f32_16x16x32_bf16(a, bw, acc[g], 0, 0, 0);
                }
            }
        }
        __syncthreads();
    }

    #pragma unroll
    for (int g = 0; g < 2; ++g) {
        int o = g * 16 + l15;
        if (o < OFFC) {
            float bo = b_off[o];
            #pragma unroll
            for (int r = 0; r < 4; ++r)
                Dsh[wav * 16 + l4 * 4 + r][o] = acc[g][r] + bo;
        }
    }
    __syncthreads();
    for (int s = tid; s < 9 * 64; s += 256) {
        int t = s >> 6, pl = s & 63;
        int pr = pr0 + pl;
        float dy = Dsh[pl][2 * t];
        float dx = Dsh[pl][2 * t + 1];
        unsigned lo = (unsigned)__half_as_ushort(__float2half(dy));
        unsigned hi = (unsigned)__half_as_ushort(__float2half(dx));
        meta2_ws[((size_t)b * 9 + t) * HW + pr] = lo | (hi << 16);
    }
}

// ---- Kernel B: w_dc fp32 -> bf16 pre-swizzled, k' = tap*256 + c ----
__global__ __launch_bounds__(256)
void wconv_kernel(const float* __restrict__ w_dc, char* __restrict__ wb)
{
    int idx = blockIdx.x * 256 + (int)threadIdx.x;   // 73728
    int o   = idx / 288;
    int rem = idx - o * 288;
    int ch  = rem >> 3;          // chunk 0..35
    int q   = rem & 7;           // q group
    int tap = ch >> 2;
    int c0  = (ch & 3) * 64 + q * 8;
    const float* wr = w_dc + (size_t)o * KDIM + (size_t)c0 * 9 + tap;
    float wv[8];
    #pragma unroll
    for (int i = 0; i < 8; ++i) wv[i] = wr[i * 9];
    uint4 pk;
    pk.x = pack2(wv[0], wv[1]); pk.y = pack2(wv[2], wv[3]);
    pk.z = pack2(wv[4], wv[5]); pk.w = pack2(wv[6], wv[7]);
    *(uint4*)(wb + (size_t)o * 4608 + ch * 128 + ((q * 16) ^ ((o & 7) << 4))) = pk;
}

// ---- Kernel C: 9-tap row-shared gather, channel-interleaved bf16 LDS tile ----
// block = (6-image-row tile [576p], 16-ch group). Xs[row][chh][col][8ch] bf16:
// one corner for 8 channels = ONE ds_read_b128 (4 b128/thread-tap vs 32 b32).
// Xs = 44.8KB + Md 20.7KB = 64KB -> 2 blocks/CU (16 waves). Staging: each
// thread owns one 16B unit (8 strided global loads -> pack -> 1 ds_write_b128,
// lanes = consecutive cols -> conflict-free). Fallback (outside 14-row window,
// ~1e-5): exact fp32 global reads.
#define GT_P   576
#define GT_WIN 14
__global__ __launch_bounds__(512, 4)
void gather_kernel9(const float* __restrict__ x,
                    const unsigned* __restrict__ meta2,
                    char* __restrict__ Vg)
{
    __shared__ __align__(16) unsigned short Xs[GT_WIN * 2 * 100 * 8]; // 44.8KB
    __shared__ unsigned Md[9 * GT_P];                                // 20.7KB

    int bid  = blockIdx.x;                    // 1024 = 8 * 128
    int fin  = (bid & 7) * 128 + (bid >> 3);  // XCD-chunked
    int tile = fin >> 4;                      // 0..63 (b*16 + trow)
    int cq   = fin & 15;                      // 0..15 (16ch each)
    int b    = tile >> 4;
    int h0   = (tile & 15) * 6;
    int c0   = cq * 16;
    int tid  = threadIdx.x;
    int prow0 = tile * GT_P;

    int r0 = h0 - 3; r0 = r0 < 0 ? 0 : (r0 > 82 ? 82 : r0);   // staged rows [r0, r0+13]

    for (int s = tid; s < 9 * GT_P; s += 512) {
        int t = s / GT_P, pl = s - t * GT_P;
        Md[s] = meta2[((size_t)b * 9 + t) * HW + h0 * WW + pl];
    }

    // stage: unit = (row, chh, col) -> 8 ch bf16 packed, one ds_write_b128
    const float* xb = x + ((size_t)b * CC + c0) * HW + r0 * WW;
    for (int s = tid; s < GT_WIN * 2 * 96; s += 512) {
        int col = s % 96;
        int rem = s / 96;
        int chh = rem & 1;
        int row = rem >> 1;
        const float* g = xb + (size_t)(chh * 8) * HW + row * WW + col;
        uint4 pk;
        pk.x = pack2(g[0],              g[(size_t)1 * HW]);
        pk.y = pack2(g[(size_t)2 * HW], g[(size_t)3 * HW]);
        pk.z = pack2(g[(size_t)4 * HW], g[(size_t)5 * HW]);
        pk.w = pack2(g[(size_t)6 * HW], g[(size_t)7 * HW]);
        *(uint4*)&Xs[(((row * 2 + chh) * 100) + col) * 8] = pk;
    }
    __syncthreads();

    const int chh  = tid & 1;                 // 8-ch slot
    const int lsub = (tid & 63) >> 1;         // 0..31 positions per wave
    const int w    = tid >> 6;                // wave 0..7
    const float* xg = x + ((size_t)b * CC + c0 + chh * 8) * HW;  // slow-path base

    for (int pass = 0; pass < 3; ++pass) {
        int i = pass * 256 + w * 32 + lsub;
        if (i >= GT_P) break;
        int oh = h0 + i / WW, ow = i - (i / WW) * WW;
        char* vrow = Vg + (size_t)(prow0 + i) * 4608 + cq * 32 +
                     ((chh * 16) ^ ((i & 1) << 4));
        #pragma unroll
        for (int t = 0; t < 9; ++t) {
            unsigned md = Md[t * GT_P + i];
            float dy = __half2float(__ushort_as_half((unsigned short)(md & 0xffffu)));
            float dx = __half2float(__ushort_as_half((unsigned short)(md >> 16)));
            float py = (float)(oh - 1 + t / 3) + dy;
            float px = (float)(ow - 1 + t % 3) + dx;
            float y0f = floorf(py), x0f = floorf(px);
            int y0 = (int)y0f, x0 = (int)x0f;
            float ly = py - y0f, lx = px - x0f;
            float wy0 = (y0 >= 0 && y0 < HH) ? 1.f - ly : 0.f;
            float wy1 = (y0 + 1 >= 0 && y0 + 1 < HH) ? ly : 0.f;
            float u0 = (x0 >= 0 && x0 < WW) ? 1.f - lx : 0.f;
            float u1 = (x0 + 1 >= 0 && x0 + 1 < WW) ? lx : 0.f;
            int pb = min(max(x0, 0), WW - 2);
            float s0, s1;
            if (x0 < 0)           { s0 = u1; s1 = 0.f; }
            else if (x0 > WW - 2) { s0 = 0.f; s1 = u0; }
            else                  { s0 = u0; s1 = u1; }
            int cy0 = min(max(y0, 0), HH - 1);
            int cy1 = min(max(y0 + 1, 0), HH - 1);
            float wa0 = wy0 * s0, wa1 = wy0 * s1;
            float wb0 = wy1 * s0, wb1 = wy1 * s1;
            float v[8];
            if (cy0 >= r0 && cy1 <= r0 + GT_WIN - 1) {
                int ra = ((cy0 - r0) * 2 + chh) * 100;
                int rb = ((cy1 - r0) * 2 + chh) * 100;
                u32x4 a0 = *(const u32x4*)&Xs[(ra + pb) * 8];
                u32x4 a1 = *(const u32x4*)&Xs[(ra + pb + 1) * 8];
                u32x4 b0 = *(const u32x4*)&Xs[(rb + pb) * 8];
                u32x4 b1 = *(const u32x4*)&Xs[(rb + pb + 1) * 8];
                #pragma unroll
                for (int k = 0; k < 8; ++k) {
                    unsigned sa0 = a0[k >> 1], sa1 = a1[k >> 1];
                    unsigned sb0 = b0[k >> 1], sb1 = b1[k >> 1];
                    float A0 = __uint_as_float((k & 1) ? (sa0 & 0xffff0000u) : (sa0 << 16));
                    float A1 = __uint_as_float((k & 1) ? (sa1 & 0xffff0000u) : (sa1 << 16));
                    float B0 = __uint_as_float((k & 1) ? (sb0 & 0xffff0000u) : (sb0 << 16));
                    float B1 = __uint_as_float((k & 1) ? (sb1 & 0xffff0000u) : (sb1 << 16));
                    v[k] = fmaf(wa0, A0, fmaf(wa1, A1, fmaf(wb0, B0, wb1 * B1)));
                }
            } else {                                   // rare exact fallback
                const float* pa = xg + cy0 * WW + pb;
                const float* pq = xg + cy1 * WW + pb;
                #pragma unroll
                for (int k = 0; k < 8; ++k) {
                    float A0 = pa[(size_t)k * HW], A1 = pa[(size_t)k * HW + 1];
                    float B0 = pq[(size_t)k * HW], B1 = pq[(size_t)k * HW + 1];
                    v[k] = fmaf(wa0, A0, fmaf(wa1, A1, fmaf(wb0, B0, wb1 * B1)));
                }
            }
            u32x4 pk;
            pk.x = pack2(v[0], v[1]); pk.y = pack2(v[2], v[3]);
            pk.z = pack2(v[4], v[5]); pk.w = pack2(v[6], v[7]);
            *(u32x4*)(vrow + t * 512) = pk;
        }
    }
}

// ---- Kernel D: streaming GEMM, 2-phase double-buffered, global_load_lds ----
// A-fragment de-swizzle = ((p&1)<<4) to match gather's 32B-granular writes.
__global__ __launch_bounds__(256)
void gemm_kernel(const char* __restrict__ Vg, const char* __restrict__ Wb,
                 const float* __restrict__ b_dc, float* __restrict__ out)
{
    __shared__ __align__(16) char Ab[2][128 * 128];
    __shared__ __align__(16) char Bb[2][128 * 128];

    int bid = blockIdx.x;
    int swzb = (bid & 7) * 72 + (bid >> 3);   // both ot of a pt share an XCD
    int pt = swzb >> 1, ot = swzb & 1;
    int tid = threadIdx.x;
    int lane = tid & 63, wav = tid >> 6;
    const int l15 = tid & 15, l4 = (tid >> 4) & 3;
    const int wp = wav >> 1, wo = wav & 1;

    const char* Ag = Vg + (size_t)(pt * 128) * 4608;
    const char* Bg = Wb + (size_t)(ot * 128) * 4608;
    const int rsub = lane >> 3;
    const int csub = (lane & 7) * 16;

    f32x4 acc[4][4];
    #pragma unroll
    for (int f = 0; f < 4; ++f)
        #pragma unroll
        for (int g = 0; g < 4; ++g)
            acc[f][g] = (f32x4){0.f, 0.f, 0.f, 0.f};

#define STAGE(bufi, t) {                                                        \
        const char* ag = Ag + (size_t)(t) * 128;                                \
        const char* bg = Bg + (size_t)(t) * 128;                                \
        _Pragma("unroll")                                                       \
        for (int i = 0; i < 4; ++i) {                                           \
            int r0 = wav * 32 + i * 8;                                          \
            gload16(ag + (size_t)(r0 + rsub) * 4608 + csub, &Ab[bufi][r0 * 128]);\
            gload16(bg + (size_t)(r0 + rsub) * 4608 + csub, &Bb[bufi][r0 * 128]);\
        } }

    STAGE(0, 0);
    __syncthreads();

    int cur = 0;
    for (int t = 0; t < NKC; ++t) {
        if (t + 1 < NKC) STAGE(cur ^ 1, t + 1);
        #pragma unroll
        for (int ks = 0; ks < 2; ++ks) {
            bf16x8 a[4], bw[4];
            #pragma unroll
            for (int f = 0; f < 4; ++f) {
                int p_loc = wp * 64 + f * 16 + l15;
                a[f] = *(const bf16x8*)(Ab[cur] + p_loc * 128 +
                                        ((ks * 64 + l4 * 16) ^ ((p_loc & 1) << 4)));
            }
            #pragma unroll
            for (int g = 0; g < 4; ++g) {
                int o_loc = wo * 64 + g * 16 + l15;
                bw[g] = *(const bf16x8*)(Bb[cur] + o_loc * 128 +
                                         ((ks * 64 + l4 * 16) ^ ((o_loc & 7) << 4)));
            }
            #pragma unroll
            for (int f = 0; f < 4; ++f)
                #pragma unroll
                for (int g = 0; g < 4; ++g)
                    acc[f][g] = __builtin_amdgcn_mfma_f32_16x16x32_bf16(a[f], bw[g], acc[f][g], 0, 0, 0);
        }
        __syncthreads();
        cur ^= 1;
    }

    int b = pt / 72;
    int posr = (pt - b * 72) * 128;
    #pragma unroll
    for (int g = 0; g < 4; ++g) {
        int og = ot * 128 + wo * 64 + g * 16 + l15;
        float bias = b_dc[og];
        float* op = out + ((size_t)b * OO + og) * HW + posr + wp * 64 + l4 * 4;
        #pragma unroll
        for (int f = 0; f < 4; ++f) {
            f32x4 r = acc[f][g];
            float4 st;
            st.x = r[0] + bias; st.y = r[1] + bias;
            st.z = r[2] + bias; st.w = r[3] + bias;
            *(float4*)(op + f * 16) = st;
        }
    }
}

// ================= FALLBACK PATH (round-2, verified) =================

__global__ __launch_bounds__(256)
void offset_conv6_kernel(const float* __restrict__ x,
                         const float* __restrict__ w_off,
                         const float* __restrict__ b_off,
                         float* __restrict__ off)
{
    int bid   = blockIdx.x;
    int g     = bid % 3;
    int chunk = (bid / 3) % 36;
    int b     = bid / 108;
    int ocb   = g * 6;
    int pr    = chunk * 256 + (int)threadIdx.x;
    int oh    = pr / WW, ow = pr % WW;
    const float* xb = x + (size_t)b * CC * HW;

    float acc[6];
    #pragma unroll
    for (int i = 0; i < 6; ++i) acc[i] = b_off[ocb + i];

    bool interior = (oh >= 1) & (oh < HH - 1) & (ow >= 1) & (ow < WW - 1);
    if (interior) {
        const float* xp = xb + (oh - 1) * WW + (ow - 1);
        float xv[9];
        #pragma unroll
        for (int t = 0; t < 9; ++t) xv[t] = xp[(t / 3) * WW + (t % 3)];
        for (int c = 0; c < CC; ++c) {
            float xn[9];
            if (c + 1 < CC) {
                const float* xq = xp + (size_t)(c + 1) * HW;
                #pragma unroll
                for (int t = 0; t < 9; ++t) xn[t] = xq[(t / 3) * WW + (t % 3)];
            }
            #pragma unroll
            for (int i = 0; i < 6; ++i) {
                const float* wr = w_off + ((size_t)(ocb + i) * CC + c) * 9;
                #pragma unroll
                for (int t = 0; t < 9; ++t)
                    acc[i] = fmaf(xv[t], wr[t], acc[i]);
            }
            #pragma unroll
            for (int t = 0; t < 9; ++t) xv[t] = xn[t];
        }
    } else {
        for (int c = 0; c < CC; ++c) {
            const float* xc = xb + (size_t)c * HW;
            float xv[9];
            #pragma unroll
            for (int t = 0; t < 9; ++t) {
                int yy = oh + t / 3 - 1, xx = ow + t % 3 - 1;
                xv[t] = (yy >= 0 && yy < HH && xx >= 0 && xx < WW) ? xc[yy * WW + xx] : 0.f;
            }
            #pragma unroll
            for (int i = 0; i < 6; ++i) {
                const float* wr = w_off + ((size_t)(ocb + i) * CC + c) * 9;
                #pragma unroll
                for (int t = 0; t < 9; ++t)
                    acc[i] = fmaf(xv[t], wr[t], acc[i]);
            }
        }
    }
    #pragma unroll
    for (int i = 0; i < 6; ++i)
        off[((size_t)b * OFFC + ocb + i) * HW + pr] = acc[i];
}

__global__ __launch_bounds__(256)
void deform_mfma_kernel(const float* __restrict__ x,
                        const float* __restrict__ off,
                        const float* __restrict__ w_dc,
                        const float* __restrict__ b_dc,
                        float* __restrict__ out)
{
    __shared__ __align__(16) char VlB[128 * 128];
    __shared__ __align__(16) char WlB[128 * 128];
    __shared__ uint4 meta[9][128];

    const int tid  = threadIdx.x;
    const int ot   = blockIdx.x / 288;
    const int pt   = blockIdx.x % 288;
    const int pos0 = pt * 128;
    const int b    = pos0 / HW;
    const int posr = pos0 - b * HW;

    const float* offp = off + (size_t)b * OFFC * HW;
    for (int s = tid; s < 9 * 128; s += 256) {
        int tt = s >> 7, j = s & 127;
        int pr = posr + j;
        float dy = offp[(2 * tt) * HW + pr];
        float dx = offp[(2 * tt + 1) * HW + pr];
        meta[tt][j] = make_meta(pr, tt, dy, dx);
    }
    __syncthreads();

    const int l15 = tid & 15;
    const int l4  = (tid >> 4) & 3;
    const int wav = tid >> 6;
    const int wp  = wav >> 1, wwo = wav & 1;
    const int j     = tid & 127;
    const int khalf = tid >> 7;
    const int wo_o  = tid >> 4;
    const int wk    = (tid & 15) * 4;

    const float* wbase = w_dc + (size_t)(ot * 128) * KDIM;

    f32x4 acc[4][4];
    #pragma unroll
    for (int f = 0; f < 4; ++f)
        #pragma unroll
        for (int g = 0; g < 4; ++g)
            acc[f][g] = (f32x4){0.f, 0.f, 0.f, 0.f};

    for (int k0 = 0; k0 < KDIM; k0 += 64) {
        #pragma unroll
        for (int r = 0; r < 8; ++r) {
            int o = r * 16 + wo_o;
            const float4 wv = *(const float4*)(wbase + (size_t)o * KDIM + k0 + wk);
            uint2 u;
            u.x = pack2(wv.x, wv.y);
            u.y = pack2(wv.z, wv.w);
            *(uint2*)(WlB + o * 128 + ((wk * 2) ^ ((o & 7) << 4))) = u;
        }
        {
            unsigned kb = (unsigned)(k0 + khalf * 32);
            unsigned c  = kb / 9u;
            unsigned tt = kb - c * 9u;
            const float* xc = x + (size_t)((unsigned)b * CC + c) * HW;
            char* vrow = VlB + j * 128;
            const unsigned swz = (unsigned)((j & 7) << 4);
            #pragma unroll
            for (int g = 0; g < 4; ++g) {
                float v[8];
                #pragma unroll
                for (int e = 0; e < 8; ++e) {
                    uint4 m = meta[tt][j];
                    float A0 = xc[m.x], A1 = xc[m.x + 1];
                    float B0 = xc[m.y], B1 = xc[m.y + 1];
                    float a0 = __uint_as_float(m.z << 16);
                    float a1 = __uint_as_float(m.z & 0xffff0000u);
                    float b0 = __uint_as_float(m.w << 16);
                    float b1 = __uint_as_float(m.w & 0xffff0000u);
                    v[e] = fmaf(a0, A0, fmaf(a1, A1, fmaf(b0, B0, b1 * B1)));
                    ++tt;
                    if (tt == 9u) { tt = 0u; xc += HW; }
                }
                uint4 pk;
                pk.x = pack2(v[0], v[1]); pk.y = pack2(v[2], v[3]);
                pk.z = pack2(v[4], v[5]); pk.w = pack2(v[6], v[7]);
                *(uint4*)(vrow + (((unsigned)(khalf * 64 + g * 16)) ^ swz)) = pk;
            }
        }
        __syncthreads();

        #pragma unroll
        for (int ks = 0; ks < 2; ++ks) {
            bf16x8 a[4], bw[4];
            #pragma unroll
            for (int f = 0; f < 4; ++f) {
                int p_loc = wp * 64 + f * 16 + l15;
                a[f] = *(const bf16x8*)(VlB + p_loc * 128 +
                                        ((ks * 64 + l4 * 16) ^ ((p_loc & 7) << 4)));
            }
            #pragma unroll
            for (int g = 0; g < 4; ++g) {
                int o_loc = wwo * 64 + g * 16 + l15;
                bw[g] = *(const bf16x8*)(WlB + o_loc * 128 +
                                         ((ks * 64 + l4 * 16) ^ ((o_loc & 7) << 4)));
            }
            #pragma unroll
            for (int f = 0; f < 4; ++f)
                #pragma unroll
                for (int g = 0; g < 4; ++g)
                    acc[f][g] = __builtin_amdgcn_mfma_f32_16x16x32_bf16(a[f], bw[g], acc[f][g], 0, 0, 0);
        }
        __syncthreads();
    }

    #pragma unroll
    for (int g = 0; g < 4; ++g) {
        int og = ot * 128 + wwo * 64 + g * 16 + l15;
        float bias = b_dc[og];
        float* op = out + ((size_t)b * OO + og) * HW + posr + wp * 64 + l4 * 4;
        #pragma unroll
        for (int f = 0; f < 4; ++f) {
            f32x4 r = acc[f][g];
            float4 st;
            st.x = r[0] + bias; st.y = r[1] + bias;
            st.z = r[2] + bias; st.w = r[3] + bias;
            *(float4*)(op + f * 16) = st;
        }
    }
}

extern "C" void kernel_launch(void* const* d_in, const int* in_sizes, int n_in,
                              void* d_out, int out_size, void* d_ws, size_t ws_size,
                              hipStream_t stream)
{
    const float* x     = (const float*)d_in[0];
    const float* w_off = (const float*)d_in[1];
    const float* b_off = (const float*)d_in[2];
    const float* w_dc  = (const float*)d_in[3];
    const float* b_dc  = (const float*)d_in[4];
    float* out = (float*)d_out;

    if (ws_size >= WS_NEED) {
        char*     ws    = (char*)d_ws;
        char*     Vg    = ws;
        char*     Wb    = ws + WS_WB_OFF;
        unsigned* meta2 = (unsigned*)(ws + WS_META_OFF);
        offset_meta_kernel<<<BB * 144, 256, 0, stream>>>(x, w_off, b_off, meta2);
        wconv_kernel<<<288, 256, 0, stream>>>(w_dc, Wb);
        gather_kernel9<<<1024, 512, 0, stream>>>(x, meta2, Vg);
        gemm_kernel<<<576, 256, 0, stream>>>(Vg, Wb, b_dc, out);
    } else {
        float* off = (float*)d_ws;
        offset_conv6_kernel<<<BB * 36 * 3, 256, 0, stream>>>(x, w_off, b_off, off);
        deform_mfma_kernel<<<(OO / 128) * (BB * HW / 128), 256, 0, stream>>>(x, off, w_dc, b_dc, out);
    }
}

// Round 13
// 197.607 us; speedup vs baseline: 2.0218x; 1.2711x over previous
//
#include <hip/hip_runtime.h>
#include <hip/hip_fp16.h>
#include <math.h>

#define BB   4
#define CC   256
#define HH   96
#define WW   96
#define OO   256
#define HW   9216        // HH*WW
#define KDIM 2304        // CC*9
#define OFFC 18
#define NKC  36          // K chunks of 64

// K ordering (split path): k' = tap*256 + c (tap-major).
// V-row content swizzle: 16B unit XOR'd by ((p&1)<<4); GEMM A-read matches.

typedef short bf16x8 __attribute__((ext_vector_type(8)));
typedef float f32x4  __attribute__((ext_vector_type(4)));
typedef unsigned int u32x4 __attribute__((ext_vector_type(4)));

// ---- ws layout (split path) ----
#define WS_V_SZ    (36864ull * 4608ull)               // V bf16 [p][k'], row 4608B
#define WS_WB_OFF  WS_V_SZ
#define WS_WB_SZ   (256ull * 4608ull)                 // W bf16 [o][k'], pre-swizzled
#define WS_META_OFF (WS_WB_OFF + WS_WB_SZ)
#define WS_META_SZ (4ull * 9ull * 9216ull * 16ull)    // region; meta2 uses 1.33MB
#define WS_WOFF_OFF (WS_META_OFF + 0x200000ull)       // 144KB Woff_b in region slack
#define WS_NEED    (WS_META_OFF + WS_META_SZ)         // ~176.4 MB (unchanged)

__device__ __forceinline__ unsigned short f2bfu(float f) {
    unsigned u = __float_as_uint(f);
    unsigned r = (u + 0x7fffu + ((u >> 16) & 1u)) >> 16;   // RNE
    return (unsigned short)r;
}
__device__ __forceinline__ unsigned pack2(float lo, float hi) {
    return (unsigned)f2bfu(lo) | ((unsigned)f2bfu(hi) << 16);
}
__device__ __forceinline__ void gload16(const void* g, void* l) {
    __builtin_amdgcn_global_load_lds((const __attribute__((address_space(1))) void*)g,
                                     (__attribute__((address_space(3))) void*)l, 16, 0, 0);
}

__device__ __forceinline__ uint4 make_meta(int pr, int t, float dy, float dx) {
    int oh = pr / WW, ow = pr - oh * WW;
    float py = (float)(oh - 1 + t / 3) + dy;
    float px = (float)(ow - 1 + (t % 3)) + dx;
    float y0f = floorf(py), x0f = floorf(px);
    int y0 = (int)y0f, x0 = (int)x0f;
    float ly = py - y0f, lx = px - x0f;
    float wy0 = (y0 >= 0 && y0 < HH) ? 1.f - ly : 0.f;
    float wy1 = (y0 + 1 >= 0 && y0 + 1 < HH) ? ly : 0.f;
    float u0 = (x0 >= 0 && x0 < WW) ? 1.f - lx : 0.f;
    float u1 = (x0 + 1 >= 0 && x0 + 1 < WW) ? lx : 0.f;
    int pb = min(max(x0, 0), WW - 2);
    float s0, s1;
    if (x0 < 0)           { s0 = u1; s1 = 0.f; }
    else if (x0 > WW - 2) { s0 = 0.f; s1 = u0; }
    else                  { s0 = u0; s1 = u1; }
    int cy0 = min(max(y0, 0), HH - 1);
    int cy1 = min(max(y0 + 1, 0), HH - 1);
    uint4 m;
    m.x = (unsigned)(cy0 * WW + pb);
    m.y = (unsigned)(cy1 * WW + pb);
    m.z = pack2(wy0 * s0, wy0 * s1);
    m.w = pack2(wy1 * s0, wy1 * s1);
    return m;
}

// ================= SPLIT PATH =================

// ---- Kernel A0: w_off -> per-chunk 4KB LDS images (bf16, swizzled, rows 18..31 zero) ----
__global__ __launch_bounds__(256)
void woff_kernel(const float* __restrict__ w_off, char* __restrict__ Woff_b)
{
    int kc  = blockIdx.x;        // 36
    int tid = threadIdx.x;       // 256
    int so  = tid >> 3, sq = tid & 7;
    int tap = kc >> 2, cb = (kc & 3) * 64;
    uint4 pk; pk.x = pk.y = pk.z = pk.w = 0u;
    if (so < OFFC) {
        const float* wr = w_off + (size_t)so * KDIM + (size_t)(cb + sq * 8) * 9 + tap;
        float wv[8];
        #pragma unroll
        for (int i = 0; i < 8; ++i) wv[i] = wr[i * 9];
        pk.x = pack2(wv[0], wv[1]); pk.y = pack2(wv[2], wv[3]);
        pk.z = pack2(wv[4], wv[5]); pk.w = pack2(wv[6], wv[7]);
    }
    *(uint4*)(Woff_b + (size_t)kc * 4096 + so * 128 + ((sq * 16) ^ ((so & 7) << 4))) = pk;
}

// ---- Kernel A: offset conv via MFMA, 512 threads (8 waves), DMA'd W ----
// Wave w -> (p-frag w&3, oc-frag w>>2). W stage = linear gload16 of the
// prebuilt 4KB image (4 DMA wave-ops vs 32 scattered wave-loads).
__global__ __launch_bounds__(512)
void offset_meta_kernel2(const float* __restrict__ x,
                         const char* __restrict__ Woff_b,
                         const float* __restrict__ b_off,
                         unsigned* __restrict__ meta2_ws)
{
    __shared__ __align__(16) char Asw[64 * 128];
    __shared__ __align__(16) char Wl[32 * 128];
    __shared__ float Dsh[64][21];

    const int tid = threadIdx.x;
    const int fin = ((blockIdx.x & 7) * 72) + (blockIdx.x >> 3);  // XCD-chunked (576 = 8*72)
    const int b   = fin / 144;
    const int pr0 = (fin % 144) * 64;
    const float* xb = x + (size_t)b * CC * HW;

    const int w    = tid >> 6;      // wave 0..7
    const int l15  = tid & 15;
    const int l4   = (tid >> 4) & 3;
    const int pf   = w & 3;         // p-frag
    const int of   = w >> 2;        // oc-frag
    const int sp   = tid & 63;      // A staging: p row
    const int kq   = tid >> 6;      // A staging: c octet 0..7

    const int prg = pr0 + sp;
    const int oh = prg / WW, ow = prg - (prg / WW) * WW;

    f32x4 acc = (f32x4){0.f, 0.f, 0.f, 0.f};

    for (int kc = 0; kc < NKC; ++kc) {
        const int tap = kc >> 2;
        const int cb  = (kc & 3) * 64;
        // W stage: linear DMA copy of prebuilt image (waves 0..3, 1KB each)
        if (w < 4)
            gload16(Woff_b + (size_t)kc * 4096 + (size_t)tid * 16, Wl + w * 1024);
        // A stage: 8 c per thread, fixed tap -> bounds once, coalesced over p
        {
            int iy = oh + tap / 3 - 1;
            int ix = ow + tap % 3 - 1;
            bool ok = (iy >= 0) & (iy < HH) & (ix >= 0) & (ix < WW);
            const float* xp = xb + (size_t)(cb + kq * 8) * HW + iy * WW + ix;
            float v[8];
            #pragma unroll
            for (int e = 0; e < 8; ++e)
                v[e] = ok ? xp[(size_t)e * HW] : 0.f;
            uint4 pk;
            pk.x = pack2(v[0], v[1]); pk.y = pack2(v[2], v[3]);
            pk.z = pack2(v[4], v[5]); pk.w = pack2(v[6], v[7]);
            *(uint4*)(Asw + sp * 128 + ((kq * 16) ^ ((sp & 7) << 4))) = pk;
        }
        __syncthreads();
        // MFMA: wave (pf, of), 2 k-steps
        {
            int p_loc = pf * 16 + l15;
            unsigned aswz = (unsigned)((p_loc & 7) << 4);
            int o_loc = of * 16 + l15;
            unsigned oswz = (unsigned)((o_loc & 7) << 4);
            #pragma unroll
            for (int ks = 0; ks < 2; ++ks) {
                bf16x8 a  = *(const bf16x8*)(Asw + p_loc * 128 + ((ks * 64 + l4 * 16) ^ aswz));
                bf16x8 bw = *(const bf16x8*)(Wl + o_loc * 128 + ((ks * 64 + l4 * 16) ^ oswz));
                acc = __builtin_amdgcn_mfma_f32_16x16x32_bf16(a, bw, acc, 0, 0, 0);
            }
        }
        __syncthreads();
    }

    // D -> LDS (rows p, cols oc<18), add bias
    {
        int o = of * 16 + l15;
        if (o < OFFC) {
            float bo = b_off[o];
            #pragma unroll
            for (int r = 0; r < 4; ++r)
                Dsh[pf * 16 + l4 * 4 + r][o] = acc[r] + bo;
        }
    }
    __syncthreads();
    for (int s = tid; s < 9 * 64; s += 512) {
        int t = s >> 6, pl = s & 63;
        int pr = pr0 + pl;
        float dy = Dsh[pl][2 * t];
        float dx = Dsh[pl][2 * t + 1];
        unsigned lo = (unsigned)__half_as_ushort(__float2half(dy));
        unsigned hi = (unsigned)__half_as_ushort(__float2half(dx));
        meta2_ws[((size_t)b * 9 + t) * HW + pr] = lo | (hi << 16);
    }
}

// ---- Kernel B: w_dc fp32 -> bf16 pre-swizzled, k' = tap*256 + c ----
__global__ __launch_bounds__(256)
void wconv_kernel(const float* __restrict__ w_dc, char* __restrict__ wb)
{
    int idx = blockIdx.x * 256 + (int)threadIdx.x;   // 73728
    int o   = idx / 288;
    int rem = idx - o * 288;
    int ch  = rem >> 3;          // chunk 0..35
    int q   = rem & 7;           // q group
    int tap = ch >> 2;
    int c0  = (ch & 3) * 64 + q * 8;
    const float* wr = w_dc + (size_t)o * KDIM + (size_t)c0 * 9 + tap;
    float wv[8];
    #pragma unroll
    for (int i = 0; i < 8; ++i) wv[i] = wr[i * 9];
    uint4 pk;
    pk.x = pack2(wv[0], wv[1]); pk.y = pack2(wv[2], wv[3]);
    pk.z = pack2(wv[4], wv[5]); pk.w = pack2(wv[6], wv[7]);
    *(uint4*)(wb + (size_t)o * 4608 + ch * 128 + ((q * 16) ^ ((o & 7) << 4))) = pk;
}

// ---- Kernel C: 9-tap row-shared gather, channel-interleaved bf16 LDS tile ----
#define GT_P   576
#define GT_WIN 14
__global__ __launch_bounds__(512, 4)
void gather_kernel9(const float* __restrict__ x,
                    const unsigned* __restrict__ meta2,
                    char* __restrict__ Vg)
{
    __shared__ __align__(16) unsigned short Xs[GT_WIN * 2 * 100 * 8]; // 44.8KB
    __shared__ unsigned Md[9 * GT_P];                                // 20.7KB

    int bid  = blockIdx.x;                    // 1024 = 8 * 128
    int fin  = (bid & 7) * 128 + (bid >> 3);  // XCD-chunked
    int tile = fin >> 4;                      // 0..63 (b*16 + trow)
    int cq   = fin & 15;                      // 0..15 (16ch each)
    int b    = tile >> 4;
    int h0   = (tile & 15) * 6;
    int c0   = cq * 16;
    int tid  = threadIdx.x;
    int prow0 = tile * GT_P;

    int r0 = h0 - 3; r0 = r0 < 0 ? 0 : (r0 > 82 ? 82 : r0);   // staged rows [r0, r0+13]

    for (int s = tid; s < 9 * GT_P; s += 512) {
        int t = s / GT_P, pl = s - t * GT_P;
        Md[s] = meta2[((size_t)b * 9 + t) * HW + h0 * WW + pl];
    }

    // stage: unit = (row, chh, col) -> 8 ch bf16 packed, one ds_write_b128
    const float* xb = x + ((size_t)b * CC + c0) * HW + r0 * WW;
    for (int s = tid; s < GT_WIN * 2 * 96; s += 512) {
        int col = s % 96;
        int rem = s / 96;
        int chh = rem & 1;
        int row = rem >> 1;
        const float* g = xb + (size_t)(chh * 8) * HW + row * WW + col;
        uint4 pk;
        pk.x = pack2(g[0],              g[(size_t)1 * HW]);
        pk.y = pack2(g[(size_t)2 * HW], g[(size_t)3 * HW]);
        pk.z = pack2(g[(size_t)4 * HW], g[(size_t)5 * HW]);
        pk.w = pack2(g[(size_t)6 * HW], g[(size_t)7 * HW]);
        *(uint4*)&Xs[(((row * 2 + chh) * 100) + col) * 8] = pk;
    }
    __syncthreads();

    const int chh  = tid & 1;                 // 8-ch slot
    const int lsub = (tid & 63) >> 1;         // 0..31 positions per wave
    const int w    = tid >> 6;                // wave 0..7
    const float* xg = x + ((size_t)b * CC + c0 + chh * 8) * HW;  // slow-path base

    for (int pass = 0; pass < 3; ++pass) {
        int i = pass * 256 + w * 32 + lsub;
        if (i >= GT_P) break;
        int oh = h0 + i / WW, ow = i - (i / WW) * WW;
        char* vrow = Vg + (size_t)(prow0 + i) * 4608 + cq * 32 +
                     ((chh * 16) ^ ((i & 1) << 4));
        #pragma unroll
        for (int t = 0; t < 9; ++t) {
            unsigned md = Md[t * GT_P + i];
            float dy = __half2float(__ushort_as_half((unsigned short)(md & 0xffffu)));
            float dx = __half2float(__ushort_as_half((unsigned short)(md >> 16)));
            float py = (float)(oh - 1 + t / 3) + dy;
            float px = (float)(ow - 1 + t % 3) + dx;
            float y0f = floorf(py), x0f = floorf(px);
            int y0 = (int)y0f, x0 = (int)x0f;
            float ly = py - y0f, lx = px - x0f;
            float wy0 = (y0 >= 0 && y0 < HH) ? 1.f - ly : 0.f;
            float wy1 = (y0 + 1 >= 0 && y0 + 1 < HH) ? ly : 0.f;
            float u0 = (x0 >= 0 && x0 < WW) ? 1.f - lx : 0.f;
            float u1 = (x0 + 1 >= 0 && x0 + 1 < WW) ? lx : 0.f;
            int pb = min(max(x0, 0), WW - 2);
            float s0, s1;
            if (x0 < 0)           { s0 = u1; s1 = 0.f; }
            else if (x0 > WW - 2) { s0 = 0.f; s1 = u0; }
            else                  { s0 = u0; s1 = u1; }
            int cy0 = min(max(y0, 0), HH - 1);
            int cy1 = min(max(y0 + 1, 0), HH - 1);
            float wa0 = wy0 * s0, wa1 = wy0 * s1;
            float wb0 = wy1 * s0, wb1 = wy1 * s1;
            float v[8];
            if (cy0 >= r0 && cy1 <= r0 + GT_WIN - 1) {
                int ra = ((cy0 - r0) * 2 + chh) * 100;
                int rb = ((cy1 - r0) * 2 + chh) * 100;
                u32x4 a0 = *(const u32x4*)&Xs[(ra + pb) * 8];
                u32x4 a1 = *(const u32x4*)&Xs[(ra + pb + 1) * 8];
                u32x4 b0 = *(const u32x4*)&Xs[(rb + pb) * 8];
                u32x4 b1 = *(const u32x4*)&Xs[(rb + pb + 1) * 8];
                #pragma unroll
                for (int k = 0; k < 8; ++k) {
                    unsigned sa0 = a0[k >> 1], sa1 = a1[k >> 1];
                    unsigned sb0 = b0[k >> 1], sb1 = b1[k >> 1];
                    float A0 = __uint_as_float((k & 1) ? (sa0 & 0xffff0000u) : (sa0 << 16));
                    float A1 = __uint_as_float((k & 1) ? (sa1 & 0xffff0000u) : (sa1 << 16));
                    float B0 = __uint_as_float((k & 1) ? (sb0 & 0xffff0000u) : (sb0 << 16));
                    float B1 = __uint_as_float((k & 1) ? (sb1 & 0xffff0000u) : (sb1 << 16));
                    v[k] = fmaf(wa0, A0, fmaf(wa1, A1, fmaf(wb0, B0, wb1 * B1)));
                }
            } else {                                   // rare exact fallback
                const float* pa = xg + cy0 * WW + pb;
                const float* pq = xg + cy1 * WW + pb;
                #pragma unroll
                for (int k = 0; k < 8; ++k) {
                    float A0 = pa[(size_t)k * HW], A1 = pa[(size_t)k * HW + 1];
                    float B0 = pq[(size_t)k * HW], B1 = pq[(size_t)k * HW + 1];
                    v[k] = fmaf(wa0, A0, fmaf(wa1, A1, fmaf(wb0, B0, wb1 * B1)));
                }
            }
            u32x4 pk;
            pk.x = pack2(v[0], v[1]); pk.y = pack2(v[2], v[3]);
            pk.z = pack2(v[4], v[5]); pk.w = pack2(v[6], v[7]);
            *(u32x4*)(vrow + t * 512) = pk;
        }
    }
}

// ---- Kernel D: streaming GEMM, 2-phase double-buffered, global_load_lds ----
// A-fragment de-swizzle = ((p&1)<<4) to match gather's 32B-granular writes.
__global__ __launch_bounds__(256)
void gemm_kernel(const char* __restrict__ Vg, const char* __restrict__ Wb,
                 const float* __restrict__ b_dc, float* __restrict__ out)
{
    __shared__ __align__(16) char Ab[2][128 * 128];
    __shared__ __align__(16) char Bb[2][128 * 128];

    int bid = blockIdx.x;
    int swzb = (bid & 7) * 72 + (bid >> 3);   // both ot of a pt share an XCD
    int pt = swzb >> 1, ot = swzb & 1;
    int tid = threadIdx.x;
    int lane = tid & 63, wav = tid >> 6;
    const int l15 = tid & 15, l4 = (tid >> 4) & 3;
    const int wp = wav >> 1, wo = wav & 1;

    const char* Ag = Vg + (size_t)(pt * 128) * 4608;
    const char* Bg = Wb + (size_t)(ot * 128) * 4608;
    const int rsub = lane >> 3;
    const int csub = (lane & 7) * 16;

    f32x4 acc[4][4];
    #pragma unroll
    for (int f = 0; f < 4; ++f)
        #pragma unroll
        for (int g = 0; g < 4; ++g)
            acc[f][g] = (f32x4){0.f, 0.f, 0.f, 0.f};

#define STAGE(bufi, t) {                                                        \
        const char* ag = Ag + (size_t)(t) * 128;                                \
        const char* bg = Bg + (size_t)(t) * 128;                                \
        _Pragma("unroll")                                                       \
        for (int i = 0; i < 4; ++i) {                                           \
            int r0 = wav * 32 + i * 8;                                          \
            gload16(ag + (size_t)(r0 + rsub) * 4608 + csub, &Ab[bufi][r0 * 128]);\
            gload16(bg + (size_t)(r0 + rsub) * 4608 + csub, &Bb[bufi][r0 * 128]);\
        } }

    STAGE(0, 0);
    __syncthreads();

    int cur = 0;
    for (int t = 0; t < NKC; ++t) {
        if (t + 1 < NKC) STAGE(cur ^ 1, t + 1);
        #pragma unroll
        for (int ks = 0; ks < 2; ++ks) {
            bf16x8 a[4], bw[4];
            #pragma unroll
            for (int f = 0; f < 4; ++f) {
                int p_loc = wp * 64 + f * 16 + l15;
                a[f] = *(const bf16x8*)(Ab[cur] + p_loc * 128 +
                                        ((ks * 64 + l4 * 16) ^ ((p_loc & 1) << 4)));
            }
            #pragma unroll
            for (int g = 0; g < 4; ++g) {
                int o_loc = wo * 64 + g * 16 + l15;
                bw[g] = *(const bf16x8*)(Bb[cur] + o_loc * 128 +
                                         ((ks * 64 + l4 * 16) ^ ((o_loc & 7) << 4)));
            }
            #pragma unroll
            for (int f = 0; f < 4; ++f)
                #pragma unroll
                for (int g = 0; g < 4; ++g)
                    acc[f][g] = __builtin_amdgcn_mfma_f32_16x16x32_bf16(a[f], bw[g], acc[f][g], 0, 0, 0);
        }
        __syncthreads();
        cur ^= 1;
    }

    int b = pt / 72;
    int posr = (pt - b * 72) * 128;
    #pragma unroll
    for (int g = 0; g < 4; ++g) {
        int og = ot * 128 + wo * 64 + g * 16 + l15;
        float bias = b_dc[og];
        float* op = out + ((size_t)b * OO + og) * HW + posr + wp * 64 + l4 * 4;
        #pragma unroll
        for (int f = 0; f < 4; ++f) {
            f32x4 r = acc[f][g];
            float4 st;
            st.x = r[0] + bias; st.y = r[1] + bias;
            st.z = r[2] + bias; st.w = r[3] + bias;
            *(float4*)(op + f * 16) = st;
        }
    }
}

// ================= FALLBACK PATH (round-2, verified) =================

__global__ __launch_bounds__(256)
void offset_conv6_kernel(const float* __restrict__ x,
                         const float* __restrict__ w_off,
                         const float* __restrict__ b_off,
                         float* __restrict__ off)
{
    int bid   = blockIdx.x;
    int g     = bid % 3;
    int chunk = (bid / 3) % 36;
    int b     = bid / 108;
    int ocb   = g * 6;
    int pr    = chunk * 256 + (int)threadIdx.x;
    int oh    = pr / WW, ow = pr % WW;
    const float* xb = x + (size_t)b * CC * HW;

    float acc[6];
    #pragma unroll
    for (int i = 0; i < 6; ++i) acc[i] = b_off[ocb + i];

    bool interior = (oh >= 1) & (oh < HH - 1) & (ow >= 1) & (ow < WW - 1);
    if (interior) {
        const float* xp = xb + (oh - 1) * WW + (ow - 1);
        float xv[9];
        #pragma unroll
        for (int t = 0; t < 9; ++t) xv[t] = xp[(t / 3) * WW + (t % 3)];
        for (int c = 0; c < CC; ++c) {
            float xn[9];
            if (c + 1 < CC) {
                const float* xq = xp + (size_t)(c + 1) * HW;
                #pragma unroll
                for (int t = 0; t < 9; ++t) xn[t] = xq[(t / 3) * WW + (t % 3)];
            }
            #pragma unroll
            for (int i = 0; i < 6; ++i) {
                const float* wr = w_off + ((size_t)(ocb + i) * CC + c) * 9;
                #pragma unroll
                for (int t = 0; t < 9; ++t)
                    acc[i] = fmaf(xv[t], wr[t], acc[i]);
            }
            #pragma unroll
            for (int t = 0; t < 9; ++t) xv[t] = xn[t];
        }
    } else {
        for (int c = 0; c < CC; ++c) {
            const float* xc = xb + (size_t)c * HW;
            float xv[9];
            #pragma unroll
            for (int t = 0; t < 9; ++t) {
                int yy = oh + t / 3 - 1, xx = ow + t % 3 - 1;
                xv[t] = (yy >= 0 && yy < HH && xx >= 0 && xx < WW) ? xc[yy * WW + xx] : 0.f;
            }
            #pragma unroll
            for (int i = 0; i < 6; ++i) {
                const float* wr = w_off + ((size_t)(ocb + i) * CC + c) * 9;
                #pragma unroll
                for (int t = 0; t < 9; ++t)
                    acc[i] = fmaf(xv[t], wr[t], acc[i]);
            }
        }
    }
    #pragma unroll
    for (int i = 0; i < 6; ++i)
        off[((size_t)b * OFFC + ocb + i) * HW + pr] = acc[i];
}

__global__ __launch_bounds__(256)
void deform_mfma_kernel(const float* __restrict__ x,
                        const float* __restrict__ off,
                        const float* __restrict__ w_dc,
                        const float* __restrict__ b_dc,
                        float* __restrict__ out)
{
    __shared__ __align__(16) char VlB[128 * 128];
    __shared__ __align__(16) char WlB[128 * 128];
    __shared__ uint4 meta[9][128];

    const int tid  = threadIdx.x;
    const int ot   = blockIdx.x / 288;
    const int pt   = blockIdx.x % 288;
    const int pos0 = pt * 128;
    const int b    = pos0 / HW;
    const int posr = pos0 - b * HW;

    const float* offp = off + (size_t)b * OFFC * HW;
    for (int s = tid; s < 9 * 128; s += 256) {
        int tt = s >> 7, j = s & 127;
        int pr = posr + j;
        float dy = offp[(2 * tt) * HW + pr];
        float dx = offp[(2 * tt + 1) * HW + pr];
        meta[tt][j] = make_meta(pr, tt, dy, dx);
    }
    __syncthreads();

    const int l15 = tid & 15;
    const int l4  = (tid >> 4) & 3;
    const int wav = tid >> 6;
    const int wp  = wav >> 1, wwo = wav & 1;
    const int j     = tid & 127;
    const int khalf = tid >> 7;
    const int wo_o  = tid >> 4;
    const int wk    = (tid & 15) * 4;

    const float* wbase = w_dc + (size_t)(ot * 128) * KDIM;

    f32x4 acc[4][4];
    #pragma unroll
    for (int f = 0; f < 4; ++f)
        #pragma unroll
        for (int g = 0; g < 4; ++g)
            acc[f][g] = (f32x4){0.f, 0.f, 0.f, 0.f};

    for (int k0 = 0; k0 < KDIM; k0 += 64) {
        #pragma unroll
        for (int r = 0; r < 8; ++r) {
            int o = r * 16 + wo_o;
            const float4 wv = *(const float4*)(wbase + (size_t)o * KDIM + k0 + wk);
            uint2 u;
            u.x = pack2(wv.x, wv.y);
            u.y = pack2(wv.z, wv.w);
            *(uint2*)(WlB + o * 128 + ((wk * 2) ^ ((o & 7) << 4))) = u;
        }
        {
            unsigned kb = (unsigned)(k0 + khalf * 32);
            unsigned c  = kb / 9u;
            unsigned tt = kb - c * 9u;
            const float* xc = x + (size_t)((unsigned)b * CC + c) * HW;
            char* vrow = VlB + j * 128;
            const unsigned swz = (unsigned)((j & 7) << 4);
            #pragma unroll
            for (int g = 0; g < 4; ++g) {
                float v[8];
                #pragma unroll
                for (int e = 0; e < 8; ++e) {
                    uint4 m = meta[tt][j];
                    float A0 = xc[m.x], A1 = xc[m.x + 1];
                    float B0 = xc[m.y], B1 = xc[m.y + 1];
                    float a0 = __uint_as_float(m.z << 16);
                    float a1 = __uint_as_float(m.z & 0xffff0000u);
                    float b0 = __uint_as_float(m.w << 16);
                    float b1 = __uint_as_float(m.w & 0xffff0000u);
                    v[e] = fmaf(a0, A0, fmaf(a1, A1, fmaf(b0, B0, b1 * B1)));
                    ++tt;
                    if (tt == 9u) { tt = 0u; xc += HW; }
                }
                uint4 pk;
                pk.x = pack2(v[0], v[1]); pk.y = pack2(v[2], v[3]);
                pk.z = pack2(v[4], v[5]); pk.w = pack2(v[6], v[7]);
                *(uint4*)(vrow + (((unsigned)(khalf * 64 + g * 16)) ^ swz)) = pk;
            }
        }
        __syncthreads();

        #pragma unroll
        for (int ks = 0; ks < 2; ++ks) {
            bf16x8 a[4], bw[4];
            #pragma unroll
            for (int f = 0; f < 4; ++f) {
                int p_loc = wp * 64 + f * 16 + l15;
                a[f] = *(const bf16x8*)(VlB + p_loc * 128 +
                                        ((ks * 64 + l4 * 16) ^ ((p_loc & 7) << 4)));
            }
            #pragma unroll
            for (int g = 0; g < 4; ++g) {
                int o_loc = wwo * 64 + g * 16 + l15;
                bw[g] = *(const bf16x8*)(WlB + o_loc * 128 +
                                         ((ks * 64 + l4 * 16) ^ ((o_loc & 7) << 4)));
            }
            #pragma unroll
            for (int f = 0; f < 4; ++f)
                #pragma unroll
                for (int g = 0; g < 4; ++g)
                    acc[f][g] = __builtin_amdgcn_mfma_f32_16x16x32_bf16(a[f], bw[g], acc[f][g], 0, 0, 0);
        }
        __syncthreads();
    }

    #pragma unroll
    for (int g = 0; g < 4; ++g) {
        int og = ot * 128 + wwo * 64 + g * 16 + l15;
        float bias = b_dc[og];
        float* op = out + ((size_t)b * OO + og) * HW + posr + wp * 64 + l4 * 4;
        #pragma unroll
        for (int f = 0; f < 4; ++f) {
            f32x4 r = acc[f][g];
            float4 st;
            st.x = r[0] + bias; st.y = r[1] + bias;
            st.z = r[2] + bias; st.w = r[3] + bias;
            *(float4*)(op + f * 16) = st;
        }
    }
}

extern "C" void kernel_launch(void* const* d_in, const int* in_sizes, int n_in,
                              void* d_out, int out_size, void* d_ws, size_t ws_size,
                              hipStream_t stream)
{
    const float* x     = (const float*)d_in[0];
    const float* w_off = (const float*)d_in[1];
    const float* b_off = (const float*)d_in[2];
    const float* w_dc  = (const float*)d_in[3];
    const float* b_dc  = (const float*)d_in[4];
    float* out = (float*)d_out;

    if (ws_size >= WS_NEED) {
        char*     ws    = (char*)d_ws;
        char*     Vg    = ws;
        char*     Wb    = ws + WS_WB_OFF;
        unsigned* meta2 = (unsigned*)(ws + WS_META_OFF);
        char*     Woffb = ws + WS_WOFF_OFF;
        woff_kernel<<<NKC, 256, 0, stream>>>(w_off, Woffb);
        wconv_kernel<<<288, 256, 0, stream>>>(w_dc, Wb);
        offset_meta_kernel2<<<576, 512, 0, stream>>>(x, Woffb, b_off, meta2);
        gather_kernel9<<<1024, 512, 0, stream>>>(x, meta2, Vg);
        gemm_kernel<<<576, 256, 0, stream>>>(Vg, Wb, b_dc, out);
    } else {
        float* off = (float*)d_ws;
        offset_conv6_kernel<<<BB * 36 * 3, 256, 0, stream>>>(x, w_off, b_off, off);
        deform_mfma_kernel<<<(OO / 128) * (BB * HW / 128), 256, 0, stream>>>(x, off, w_dc, b_dc, out);
    }
}

// Round 14
// 196.069 us; speedup vs baseline: 2.0377x; 1.0078x over previous
//
#include <hip/hip_runtime.h>
#include <hip/hip_fp16.h>
#include <math.h>

#define BB   4
#define CC   256
#define HH   96
#define WW   96
#define OO   256
#define HW   9216        // HH*WW
#define KDIM 2304        // CC*9
#define OFFC 18
#define NKC  36          // K chunks of 64

// K ordering (split path): k' = tap*256 + c (tap-major).
// V-row content swizzle: 16B unit at logical byte lb within its 128B chunk is
// stored at physical byte lb ^ ((p&7)<<4) (gather global-scatter writes it;
// GEMM A-read de-swizzles with the same involution). B keeps (o&7)<<4.

typedef short bf16x8 __attribute__((ext_vector_type(8)));
typedef float f32x4  __attribute__((ext_vector_type(4)));
typedef unsigned int u32x4 __attribute__((ext_vector_type(4)));

// ---- ws layout (split path) ----
#define WS_V_SZ    (36864ull * 4608ull)               // V bf16 [p][k'], row 4608B
#define WS_WB_OFF  WS_V_SZ
#define WS_WB_SZ   (256ull * 4608ull)                 // W bf16 [o][k'], pre-swizzled
#define WS_META_OFF (WS_WB_OFF + WS_WB_SZ)
#define WS_META_SZ (4ull * 9ull * 9216ull * 16ull)    // region; meta2 uses 1.33MB
#define WS_WOFF_OFF (WS_META_OFF + 0x200000ull)       // 144KB Woff_b in region slack
#define WS_NEED    (WS_META_OFF + WS_META_SZ)         // ~176.4 MB (unchanged)

__device__ __forceinline__ unsigned short f2bfu(float f) {
    unsigned u = __float_as_uint(f);
    unsigned r = (u + 0x7fffu + ((u >> 16) & 1u)) >> 16;   // RNE
    return (unsigned short)r;
}
__device__ __forceinline__ unsigned pack2(float lo, float hi) {
    return (unsigned)f2bfu(lo) | ((unsigned)f2bfu(hi) << 16);
}
__device__ __forceinline__ void gload16(const void* g, void* l) {
    __builtin_amdgcn_global_load_lds((const __attribute__((address_space(1))) void*)g,
                                     (__attribute__((address_space(3))) void*)l, 16, 0, 0);
}

__device__ __forceinline__ uint4 make_meta(int pr, int t, float dy, float dx) {
    int oh = pr / WW, ow = pr - oh * WW;
    float py = (float)(oh - 1 + t / 3) + dy;
    float px = (float)(ow - 1 + (t % 3)) + dx;
    float y0f = floorf(py), x0f = floorf(px);
    int y0 = (int)y0f, x0 = (int)x0f;
    float ly = py - y0f, lx = px - x0f;
    float wy0 = (y0 >= 0 && y0 < HH) ? 1.f - ly : 0.f;
    float wy1 = (y0 + 1 >= 0 && y0 + 1 < HH) ? ly : 0.f;
    float u0 = (x0 >= 0 && x0 < WW) ? 1.f - lx : 0.f;
    float u1 = (x0 + 1 >= 0 && x0 + 1 < WW) ? lx : 0.f;
    int pb = min(max(x0, 0), WW - 2);
    float s0, s1;
    if (x0 < 0)           { s0 = u1; s1 = 0.f; }
    else if (x0 > WW - 2) { s0 = 0.f; s1 = u0; }
    else                  { s0 = u0; s1 = u1; }
    int cy0 = min(max(y0, 0), HH - 1);
    int cy1 = min(max(y0 + 1, 0), HH - 1);
    uint4 m;
    m.x = (unsigned)(cy0 * WW + pb);
    m.y = (unsigned)(cy1 * WW + pb);
    m.z = pack2(wy0 * s0, wy0 * s1);
    m.w = pack2(wy1 * s0, wy1 * s1);
    return m;
}

// ================= SPLIT PATH =================

// ---- Kernel A0: w_off -> per-chunk 4KB LDS images (bf16, swizzled, rows 18..31 zero) ----
__global__ __launch_bounds__(256)
void woff_kernel(const float* __restrict__ w_off, char* __restrict__ Woff_b)
{
    int kc  = blockIdx.x;        // 36
    int tid = threadIdx.x;       // 256
    int so  = tid >> 3, sq = tid & 7;
    int tap = kc >> 2, cb = (kc & 3) * 64;
    uint4 pk; pk.x = pk.y = pk.z = pk.w = 0u;
    if (so < OFFC) {
        const float* wr = w_off + (size_t)so * KDIM + (size_t)(cb + sq * 8) * 9 + tap;
        float wv[8];
        #pragma unroll
        for (int i = 0; i < 8; ++i) wv[i] = wr[i * 9];
        pk.x = pack2(wv[0], wv[1]); pk.y = pack2(wv[2], wv[3]);
        pk.z = pack2(wv[4], wv[5]); pk.w = pack2(wv[6], wv[7]);
    }
    *(uint4*)(Woff_b + (size_t)kc * 4096 + so * 128 + ((sq * 16) ^ ((so & 7) << 4))) = pk;
}

// ---- Kernel A: offset conv via MFMA, 512 threads (8 waves), DMA'd W ----
__global__ __launch_bounds__(512)
void offset_meta_kernel2(const float* __restrict__ x,
                         const char* __restrict__ Woff_b,
                         const float* __restrict__ b_off,
                         unsigned* __restrict__ meta2_ws)
{
    __shared__ __align__(16) char Asw[64 * 128];
    __shared__ __align__(16) char Wl[32 * 128];
    __shared__ float Dsh[64][21];

    const int tid = threadIdx.x;
    const int fin = ((blockIdx.x & 7) * 72) + (blockIdx.x >> 3);  // XCD-chunked (576 = 8*72)
    const int b   = fin / 144;
    const int pr0 = (fin % 144) * 64;
    const float* xb = x + (size_t)b * CC * HW;

    const int w    = tid >> 6;      // wave 0..7
    const int l15  = tid & 15;
    const int l4   = (tid >> 4) & 3;
    const int pf   = w & 3;         // p-frag
    const int of   = w >> 2;        // oc-frag
    const int sp   = tid & 63;      // A staging: p row
    const int kq   = tid >> 6;      // A staging: c octet 0..7

    const int prg = pr0 + sp;
    const int oh = prg / WW, ow = prg - (prg / WW) * WW;

    f32x4 acc = (f32x4){0.f, 0.f, 0.f, 0.f};

    for (int kc = 0; kc < NKC; ++kc) {
        const int tap = kc >> 2;
        const int cb  = (kc & 3) * 64;
        // W stage: linear DMA copy of prebuilt image (waves 0..3, 1KB each)
        if (w < 4)
            gload16(Woff_b + (size_t)kc * 4096 + (size_t)tid * 16, Wl + w * 1024);
        // A stage: 8 c per thread, fixed tap -> bounds once, coalesced over p
        {
            int iy = oh + tap / 3 - 1;
            int ix = ow + tap % 3 - 1;
            bool ok = (iy >= 0) & (iy < HH) & (ix >= 0) & (ix < WW);
            const float* xp = xb + (size_t)(cb + kq * 8) * HW + iy * WW + ix;
            float v[8];
            #pragma unroll
            for (int e = 0; e < 8; ++e)
                v[e] = ok ? xp[(size_t)e * HW] : 0.f;
            uint4 pk;
            pk.x = pack2(v[0], v[1]); pk.y = pack2(v[2], v[3]);
            pk.z = pack2(v[4], v[5]); pk.w = pack2(v[6], v[7]);
            *(uint4*)(Asw + sp * 128 + ((kq * 16) ^ ((sp & 7) << 4))) = pk;
        }
        __syncthreads();
        // MFMA: wave (pf, of), 2 k-steps
        {
            int p_loc = pf * 16 + l15;
            unsigned aswz = (unsigned)((p_loc & 7) << 4);
            int o_loc = of * 16 + l15;
            unsigned oswz = (unsigned)((o_loc & 7) << 4);
            #pragma unroll
            for (int ks = 0; ks < 2; ++ks) {
                bf16x8 a  = *(const bf16x8*)(Asw + p_loc * 128 + ((ks * 64 + l4 * 16) ^ aswz));
                bf16x8 bw = *(const bf16x8*)(Wl + o_loc * 128 + ((ks * 64 + l4 * 16) ^ oswz));
                acc = __builtin_amdgcn_mfma_f32_16x16x32_bf16(a, bw, acc, 0, 0, 0);
            }
        }
        __syncthreads();
    }

    // D -> LDS (rows p, cols oc<18), add bias
    {
        int o = of * 16 + l15;
        if (o < OFFC) {
            float bo = b_off[o];
            #pragma unroll
            for (int r = 0; r < 4; ++r)
                Dsh[pf * 16 + l4 * 4 + r][o] = acc[r] + bo;
        }
    }
    __syncthreads();
    for (int s = tid; s < 9 * 64; s += 512) {
        int t = s >> 6, pl = s & 63;
        int pr = pr0 + pl;
        float dy = Dsh[pl][2 * t];
        float dx = Dsh[pl][2 * t + 1];
        unsigned lo = (unsigned)__half_as_ushort(__float2half(dy));
        unsigned hi = (unsigned)__half_as_ushort(__float2half(dx));
        meta2_ws[((size_t)b * 9 + t) * HW + pr] = lo | (hi << 16);
    }
}

// ---- Kernel B: w_dc fp32 -> bf16 pre-swizzled, k' = tap*256 + c ----
__global__ __launch_bounds__(256)
void wconv_kernel(const float* __restrict__ w_dc, char* __restrict__ wb)
{
    int idx = blockIdx.x * 256 + (int)threadIdx.x;   // 73728
    int o   = idx / 288;
    int rem = idx - o * 288;
    int ch  = rem >> 3;          // chunk 0..35
    int q   = rem & 7;           // q group
    int tap = ch >> 2;
    int c0  = (ch & 3) * 64 + q * 8;
    const float* wr = w_dc + (size_t)o * KDIM + (size_t)c0 * 9 + tap;
    float wv[8];
    #pragma unroll
    for (int i = 0; i < 8; ++i) wv[i] = wr[i * 9];
    uint4 pk;
    pk.x = pack2(wv[0], wv[1]); pk.y = pack2(wv[2], wv[3]);
    pk.z = pack2(wv[4], wv[5]); pk.w = pack2(wv[6], wv[7]);
    *(uint4*)(wb + (size_t)o * 4608 + ch * 128 + ((q * 16) ^ ((o & 7) << 4))) = pk;
}

// ---- Kernel C: 9-tap row-shared gather, channel-interleaved bf16 LDS tile ----
// V-store: global scatter to the FULL 3-bit swizzled address (unit stays in
// its 128B chunk; bits 4-6 = (cq&3,chh) XOR'd by (p&7)) -> GEMM A-reads are
// conflict-free. Write granularity unchanged (16B units, lines co-filled).
#define GT_P   576
#define GT_WIN 14
__global__ __launch_bounds__(512, 4)
void gather_kernel9(const float* __restrict__ x,
                    const unsigned* __restrict__ meta2,
                    char* __restrict__ Vg)
{
    __shared__ __align__(16) unsigned short Xs[GT_WIN * 2 * 100 * 8]; // 44.8KB
    __shared__ unsigned Md[9 * GT_P];                                // 20.7KB

    int bid  = blockIdx.x;                    // 1024 = 8 * 128
    int fin  = (bid & 7) * 128 + (bid >> 3);  // XCD-chunked
    int tile = fin >> 4;                      // 0..63 (b*16 + trow)
    int cq   = fin & 15;                      // 0..15 (16ch each)
    int b    = tile >> 4;
    int h0   = (tile & 15) * 6;
    int c0   = cq * 16;
    int tid  = threadIdx.x;
    int prow0 = tile * GT_P;

    int r0 = h0 - 3; r0 = r0 < 0 ? 0 : (r0 > 82 ? 82 : r0);   // staged rows [r0, r0+13]

    for (int s = tid; s < 9 * GT_P; s += 512) {
        int t = s / GT_P, pl = s - t * GT_P;
        Md[s] = meta2[((size_t)b * 9 + t) * HW + h0 * WW + pl];
    }

    // stage: unit = (row, chh, col) -> 8 ch bf16 packed, one ds_write_b128
    const float* xb = x + ((size_t)b * CC + c0) * HW + r0 * WW;
    for (int s = tid; s < GT_WIN * 2 * 96; s += 512) {
        int col = s % 96;
        int rem = s / 96;
        int chh = rem & 1;
        int row = rem >> 1;
        const float* g = xb + (size_t)(chh * 8) * HW + row * WW + col;
        uint4 pk;
        pk.x = pack2(g[0],              g[(size_t)1 * HW]);
        pk.y = pack2(g[(size_t)2 * HW], g[(size_t)3 * HW]);
        pk.z = pack2(g[(size_t)4 * HW], g[(size_t)5 * HW]);
        pk.w = pack2(g[(size_t)6 * HW], g[(size_t)7 * HW]);
        *(uint4*)&Xs[(((row * 2 + chh) * 100) + col) * 8] = pk;
    }
    __syncthreads();

    const int chh  = tid & 1;                 // 8-ch slot
    const int lsub = (tid & 63) >> 1;         // 0..31 positions per wave
    const int w    = tid >> 6;                // wave 0..7
    const float* xg = x + ((size_t)b * CC + c0 + chh * 8) * HW;  // slow-path base
    const int chunk_hi = (cq >> 2) * 128;     // chunk within tap region
    const int base_in_chunk = (cq & 3) * 32 + chh * 16;

    for (int pass = 0; pass < 3; ++pass) {
        int i = pass * 256 + w * 32 + lsub;
        if (i >= GT_P) break;
        int oh = h0 + i / WW, ow = i - (i / WW) * WW;
        char* vrow0 = Vg + (size_t)(prow0 + i) * 4608;
        const int inchunk = base_in_chunk ^ ((i & 7) << 4);   // 3-bit content swizzle
        #pragma unroll
        for (int t = 0; t < 9; ++t) {
            unsigned md = Md[t * GT_P + i];
            float dy = __half2float(__ushort_as_half((unsigned short)(md & 0xffffu)));
            float dx = __half2float(__ushort_as_half((unsigned short)(md >> 16)));
            float py = (float)(oh - 1 + t / 3) + dy;
            float px = (float)(ow - 1 + t % 3) + dx;
            float y0f = floorf(py), x0f = floorf(px);
            int y0 = (int)y0f, x0 = (int)x0f;
            float ly = py - y0f, lx = px - x0f;
            float wy0 = (y0 >= 0 && y0 < HH) ? 1.f - ly : 0.f;
            float wy1 = (y0 + 1 >= 0 && y0 + 1 < HH) ? ly : 0.f;
            float u0 = (x0 >= 0 && x0 < WW) ? 1.f - lx : 0.f;
            float u1 = (x0 + 1 >= 0 && x0 + 1 < WW) ? lx : 0.f;
            int pb = min(max(x0, 0), WW - 2);
            float s0, s1;
            if (x0 < 0)           { s0 = u1; s1 = 0.f; }
            else if (x0 > WW - 2) { s0 = 0.f; s1 = u0; }
            else                  { s0 = u0; s1 = u1; }
            int cy0 = min(max(y0, 0), HH - 1);
            int cy1 = min(max(y0 + 1, 0), HH - 1);
            float wa0 = wy0 * s0, wa1 = wy0 * s1;
            float wb0 = wy1 * s0, wb1 = wy1 * s1;
            float v[8];
            if (cy0 >= r0 && cy1 <= r0 + GT_WIN - 1) {
                int ra = ((cy0 - r0) * 2 + chh) * 100;
                int rb = ((cy1 - r0) * 2 + chh) * 100;
                u32x4 a0 = *(const u32x4*)&Xs[(ra + pb) * 8];
                u32x4 a1 = *(const u32x4*)&Xs[(ra + pb + 1) * 8];
                u32x4 b0 = *(const u32x4*)&Xs[(rb + pb) * 8];
                u32x4 b1 = *(const u32x4*)&Xs[(rb + pb + 1) * 8];
                #pragma unroll
                for (int k = 0; k < 8; ++k) {
                    unsigned sa0 = a0[k >> 1], sa1 = a1[k >> 1];
                    unsigned sb0 = b0[k >> 1], sb1 = b1[k >> 1];
                    float A0 = __uint_as_float((k & 1) ? (sa0 & 0xffff0000u) : (sa0 << 16));
                    float A1 = __uint_as_float((k & 1) ? (sa1 & 0xffff0000u) : (sa1 << 16));
                    float B0 = __uint_as_float((k & 1) ? (sb0 & 0xffff0000u) : (sb0 << 16));
                    float B1 = __uint_as_float((k & 1) ? (sb1 & 0xffff0000u) : (sb1 << 16));
                    v[k] = fmaf(wa0, A0, fmaf(wa1, A1, fmaf(wb0, B0, wb1 * B1)));
                }
            } else {                                   // rare exact fallback
                const float* pa = xg + cy0 * WW + pb;
                const float* pq = xg + cy1 * WW + pb;
                #pragma unroll
                for (int k = 0; k < 8; ++k) {
                    float A0 = pa[(size_t)k * HW], A1 = pa[(size_t)k * HW + 1];
                    float B0 = pq[(size_t)k * HW], B1 = pq[(size_t)k * HW + 1];
                    v[k] = fmaf(wa0, A0, fmaf(wa1, A1, fmaf(wb0, B0, wb1 * B1)));
                }
            }
            u32x4 pk;
            pk.x = pack2(v[0], v[1]); pk.y = pack2(v[2], v[3]);
            pk.z = pack2(v[4], v[5]); pk.w = pack2(v[6], v[7]);
            *(u32x4*)(vrow0 + t * 512 + chunk_hi + inchunk) = pk;
        }
    }
}

// ---- Kernel D: streaming GEMM, 512 threads (8 waves = 2p x 4o), 2-phase dbuf ----
// A de-swizzle ((p&7)<<4) matches gather's 3-bit content swizzle; B ((o&7)<<4).
__global__ __launch_bounds__(512)
void gemm_kernel(const char* __restrict__ Vg, const char* __restrict__ Wb,
                 const float* __restrict__ b_dc, float* __restrict__ out)
{
    __shared__ __align__(16) char Ab[2][128 * 128];
    __shared__ __align__(16) char Bb[2][128 * 128];

    int bid = blockIdx.x;
    int swzb = (bid & 7) * 72 + (bid >> 3);   // both ot of a pt share an XCD
    int pt = swzb >> 1, ot = swzb & 1;
    int tid = threadIdx.x;
    int wav = tid >> 6;                       // 0..7
    const int l15 = tid & 15, l4 = (tid >> 4) & 3;
    const int wp = wav >> 2, wo = wav & 3;    // p-half (64), o-quarter (32)

    const char* Ag = Vg + (size_t)(pt * 128) * 4608;
    const char* Bg = Wb + (size_t)(ot * 128) * 4608;

    f32x4 acc[4][2];
    #pragma unroll
    for (int f = 0; f < 4; ++f)
        #pragma unroll
        for (int g = 0; g < 2; ++g)
            acc[f][g] = (f32x4){0.f, 0.f, 0.f, 0.f};

#define STAGE(bufi, t) {                                                         \
        const char* ag = Ag + (size_t)(t) * 128;                                 \
        const char* bg = Bg + (size_t)(t) * 128;                                 \
        _Pragma("unroll")                                                        \
        for (int i = 0; i < 2; ++i) {                                            \
            int u = i * 512 + tid;                                               \
            int row = u >> 3, cu = (u & 7) * 16;                                 \
            gload16(ag + (size_t)row * 4608 + cu,                                \
                    &Ab[bufi][(i * 512 + wav * 64) * 16]);                       \
            gload16(bg + (size_t)row * 4608 + cu,                                \
                    &Bb[bufi][(i * 512 + wav * 64) * 16]);                       \
        } }

    STAGE(0, 0);
    __syncthreads();

    int cur = 0;
    for (int t = 0; t < NKC; ++t) {
        if (t + 1 < NKC) STAGE(cur ^ 1, t + 1);
        #pragma unroll
        for (int ks = 0; ks < 2; ++ks) {
            bf16x8 a[4], bw[2];
            #pragma unroll
            for (int f = 0; f < 4; ++f) {
                int p_loc = wp * 64 + f * 16 + l15;
                a[f] = *(const bf16x8*)(Ab[cur] + p_loc * 128 +
                                        ((ks * 64 + l4 * 16) ^ ((p_loc & 7) << 4)));
            }
            #pragma unroll
            for (int g = 0; g < 2; ++g) {
                int o_loc = wo * 32 + g * 16 + l15;
                bw[g] = *(const bf16x8*)(Bb[cur] + o_loc * 128 +
                                         ((ks * 64 + l4 * 16) ^ ((o_loc & 7) << 4)));
            }
            #pragma unroll
            for (int f = 0; f < 4; ++f)
                #pragma unroll
                for (int g = 0; g < 2; ++g)
                    acc[f][g] = __builtin_amdgcn_mfma_f32_16x16x32_bf16(a[f], bw[g], acc[f][g], 0, 0, 0);
        }
        __syncthreads();
        cur ^= 1;
    }
#undef STAGE

    int b = pt / 72;
    int posr = (pt - b * 72) * 128;
    #pragma unroll
    for (int g = 0; g < 2; ++g) {
        int og = ot * 128 + wo * 32 + g * 16 + l15;
        float bias = b_dc[og];
        float* op = out + ((size_t)b * OO + og) * HW + posr + wp * 64 + l4 * 4;
        #pragma unroll
        for (int f = 0; f < 4; ++f) {
            f32x4 r = acc[f][g];
            float4 st;
            st.x = r[0] + bias; st.y = r[1] + bias;
            st.z = r[2] + bias; st.w = r[3] + bias;
            *(float4*)(op + f * 16) = st;
        }
    }
}

// ================= FALLBACK PATH (round-2, verified) =================

__global__ __launch_bounds__(256)
void offset_conv6_kernel(const float* __restrict__ x,
                         const float* __restrict__ w_off,
                         const float* __restrict__ b_off,
                         float* __restrict__ off)
{
    int bid   = blockIdx.x;
    int g     = bid % 3;
    int chunk = (bid / 3) % 36;
    int b     = bid / 108;
    int ocb   = g * 6;
    int pr    = chunk * 256 + (int)threadIdx.x;
    int oh    = pr / WW, ow = pr % WW;
    const float* xb = x + (size_t)b * CC * HW;

    float acc[6];
    #pragma unroll
    for (int i = 0; i < 6; ++i) acc[i] = b_off[ocb + i];

    bool interior = (oh >= 1) & (oh < HH - 1) & (ow >= 1) & (ow < WW - 1);
    if (interior) {
        const float* xp = xb + (oh - 1) * WW + (ow - 1);
        float xv[9];
        #pragma unroll
        for (int t = 0; t < 9; ++t) xv[t] = xp[(t / 3) * WW + (t % 3)];
        for (int c = 0; c < CC; ++c) {
            float xn[9];
            if (c + 1 < CC) {
                const float* xq = xp + (size_t)(c + 1) * HW;
                #pragma unroll
                for (int t = 0; t < 9; ++t) xn[t] = xq[(t / 3) * WW + (t % 3)];
            }
            #pragma unroll
            for (int i = 0; i < 6; ++i) {
                const float* wr = w_off + ((size_t)(ocb + i) * CC + c) * 9;
                #pragma unroll
                for (int t = 0; t < 9; ++t)
                    acc[i] = fmaf(xv[t], wr[t], acc[i]);
            }
            #pragma unroll
            for (int t = 0; t < 9; ++t) xv[t] = xn[t];
        }
    } else {
        for (int c = 0; c < CC; ++c) {
            const float* xc = xb + (size_t)c * HW;
            float xv[9];
            #pragma unroll
            for (int t = 0; t < 9; ++t) {
                int yy = oh + t / 3 - 1, xx = ow + t % 3 - 1;
                xv[t] = (yy >= 0 && yy < HH && xx >= 0 && xx < WW) ? xc[yy * WW + xx] : 0.f;
            }
            #pragma unroll
            for (int i = 0; i < 6; ++i) {
                const float* wr = w_off + ((size_t)(ocb + i) * CC + c) * 9;
                #pragma unroll
                for (int t = 0; t < 9; ++t)
                    acc[i] = fmaf(xv[t], wr[t], acc[i]);
            }
        }
    }
    #pragma unroll
    for (int i = 0; i < 6; ++i)
        off[((size_t)b * OFFC + ocb + i) * HW + pr] = acc[i];
}

__global__ __launch_bounds__(256)
void deform_mfma_kernel(const float* __restrict__ x,
                        const float* __restrict__ off,
                        const float* __restrict__ w_dc,
                        const float* __restrict__ b_dc,
                        float* __restrict__ out)
{
    __shared__ __align__(16) char VlB[128 * 128];
    __shared__ __align__(16) char WlB[128 * 128];
    __shared__ uint4 meta[9][128];

    const int tid  = threadIdx.x;
    const int ot   = blockIdx.x / 288;
    const int pt   = blockIdx.x % 288;
    const int pos0 = pt * 128;
    const int b    = pos0 / HW;
    const int posr = pos0 - b * HW;

    const float* offp = off + (size_t)b * OFFC * HW;
    for (int s = tid; s < 9 * 128; s += 256) {
        int tt = s >> 7, j = s & 127;
        int pr = posr + j;
        float dy = offp[(2 * tt) * HW + pr];
        float dx = offp[(2 * tt + 1) * HW + pr];
        meta[tt][j] = make_meta(pr, tt, dy, dx);
    }
    __syncthreads();

    const int l15 = tid & 15;
    const int l4  = (tid >> 4) & 3;
    const int wav = tid >> 6;
    const int wp  = wav >> 1, wwo = wav & 1;
    const int j     = tid & 127;
    const int khalf = tid >> 7;
    const int wo_o  = tid >> 4;
    const int wk    = (tid & 15) * 4;

    const float* wbase = w_dc + (size_t)(ot * 128) * KDIM;

    f32x4 acc[4][4];
    #pragma unroll
    for (int f = 0; f < 4; ++f)
        #pragma unroll
        for (int g = 0; g < 4; ++g)
            acc[f][g] = (f32x4){0.f, 0.f, 0.f, 0.f};

    for (int k0 = 0; k0 < KDIM; k0 += 64) {
        #pragma unroll
        for (int r = 0; r < 8; ++r) {
            int o = r * 16 + wo_o;
            const float4 wv = *(const float4*)(wbase + (size_t)o * KDIM + k0 + wk);
            uint2 u;
            u.x = pack2(wv.x, wv.y);
            u.y = pack2(wv.z, wv.w);
            *(uint2*)(WlB + o * 128 + ((wk * 2) ^ ((o & 7) << 4))) = u;
        }
        {
            unsigned kb = (unsigned)(k0 + khalf * 32);
            unsigned c  = kb / 9u;
            unsigned tt = kb - c * 9u;
            const float* xc = x + (size_t)((unsigned)b * CC + c) * HW;
            char* vrow = VlB + j * 128;
            const unsigned swz = (unsigned)((j & 7) << 4);
            #pragma unroll
            for (int g = 0; g < 4; ++g) {
                float v[8];
                #pragma unroll
                for (int e = 0; e < 8; ++e) {
                    uint4 m = meta[tt][j];
                    float A0 = xc[m.x], A1 = xc[m.x + 1];
                    float B0 = xc[m.y], B1 = xc[m.y + 1];
                    float a0 = __uint_as_float(m.z << 16);
                    float a1 = __uint_as_float(m.z & 0xffff0000u);
                    float b0 = __uint_as_float(m.w << 16);
                    float b1 = __uint_as_float(m.w & 0xffff0000u);
                    v[e] = fmaf(a0, A0, fmaf(a1, A1, fmaf(b0, B0, b1 * B1)));
                    ++tt;
                    if (tt == 9u) { tt = 0u; xc += HW; }
                }
                uint4 pk;
                pk.x = pack2(v[0], v[1]); pk.y = pack2(v[2], v[3]);
                pk.z = pack2(v[4], v[5]); pk.w = pack2(v[6], v[7]);
                *(uint4*)(vrow + (((unsigned)(khalf * 64 + g * 16)) ^ swz)) = pk;
            }
        }
        __syncthreads();

        #pragma unroll
        for (int ks = 0; ks < 2; ++ks) {
            bf16x8 a[4], bw[4];
            #pragma unroll
            for (int f = 0; f < 4; ++f) {
                int p_loc = wp * 64 + f * 16 + l15;
                a[f] = *(const bf16x8*)(VlB + p_loc * 128 +
                                        ((ks * 64 + l4 * 16) ^ ((p_loc & 7) << 4)));
            }
            #pragma unroll
            for (int g = 0; g < 4; ++g) {
                int o_loc = wwo * 64 + g * 16 + l15;
                bw[g] = *(const bf16x8*)(WlB + o_loc * 128 +
                                         ((ks * 64 + l4 * 16) ^ ((o_loc & 7) << 4)));
            }
            #pragma unroll
            for (int f = 0; f < 4; ++f)
                #pragma unroll
                for (int g = 0; g < 4; ++g)
                    acc[f][g] = __builtin_amdgcn_mfma_f32_16x16x32_bf16(a[f], bw[g], acc[f][g], 0, 0, 0);
        }
        __syncthreads();
    }

    #pragma unroll
    for (int g = 0; g < 4; ++g) {
        int og = ot * 128 + wwo * 64 + g * 16 + l15;
        float bias = b_dc[og];
        float* op = out + ((size_t)b * OO + og) * HW + posr + wp * 64 + l4 * 4;
        #pragma unroll
        for (int f = 0; f < 4; ++f) {
            f32x4 r = acc[f][g];
            float4 st;
            st.x = r[0] + bias; st.y = r[1] + bias;
            st.z = r[2] + bias; st.w = r[3] + bias;
            *(float4*)(op + f * 16) = st;
        }
    }
}

extern "C" void kernel_launch(void* const* d_in, const int* in_sizes, int n_in,
                              void* d_out, int out_size, void* d_ws, size_t ws_size,
                              hipStream_t stream)
{
    const float* x     = (const float*)d_in[0];
    const float* w_off = (const float*)d_in[1];
    const float* b_off = (const float*)d_in[2];
    const float* w_dc  = (const float*)d_in[3];
    const float* b_dc  = (const float*)d_in[4];
    float* out = (float*)d_out;

    if (ws_size >= WS_NEED) {
        char*     ws    = (char*)d_ws;
        char*     Vg    = ws;
        char*     Wb    = ws + WS_WB_OFF;
        unsigned* meta2 = (unsigned*)(ws + WS_META_OFF);
        char*     Woffb = ws + WS_WOFF_OFF;
        woff_kernel<<<NKC, 256, 0, stream>>>(w_off, Woffb);
        wconv_kernel<<<288, 256, 0, stream>>>(w_dc, Wb);
        offset_meta_kernel2<<<576, 512, 0, stream>>>(x, Woffb, b_off, meta2);
        gather_kernel9<<<1024, 512, 0, stream>>>(x, meta2, Vg);
        gemm_kernel<<<576, 512, 0, stream>>>(Vg, Wb, b_dc, out);
    } else {
        float* off = (float*)d_ws;
        offset_conv6_kernel<<<BB * 36 * 3, 256, 0, stream>>>(x, w_off, b_off, off);
        deform_mfma_kernel<<<(OO / 128) * (BB * HW / 128), 256, 0, stream>>>(x, off, w_dc, b_dc, out);
    }
}

// Round 15
// 179.430 us; speedup vs baseline: 2.2266x; 1.0927x over previous
//
#include <hip/hip_runtime.h>
#include <hip/hip_fp16.h>
#include <math.h>

#define BB   4
#define CC   256
#define HH   96
#define WW   96
#define OO   256
#define HW   9216        // HH*WW
#define KDIM 2304        // CC*9
#define OFFC 18
#define NKC  36          // K chunks of 64

// K ordering (split path): k' = tap*256 + c (tap-major).
// V-row content swizzle: 16B unit at logical byte lb within its 128B chunk is
// stored at physical byte lb ^ ((p&7)<<4); GEMM A-read de-swizzles. B: (o&7)<<4.

typedef short bf16x8 __attribute__((ext_vector_type(8)));
typedef float f32x4  __attribute__((ext_vector_type(4)));
typedef unsigned int u32x4 __attribute__((ext_vector_type(4)));

// ---- ws layout (split path) ----
#define WS_V_SZ    (36864ull * 4608ull)               // V bf16 [p][k'], row 4608B
#define WS_WB_OFF  WS_V_SZ
#define WS_WB_SZ   (256ull * 4608ull)                 // W bf16 [o][k'], pre-swizzled
#define WS_META_OFF (WS_WB_OFF + WS_WB_SZ)
#define WS_META_SZ (4ull * 9ull * 9216ull * 16ull)    // region; meta2 uses 1.33MB
#define WS_WOFF_OFF (WS_META_OFF + 0x200000ull)       // 144KB Woff_b in region slack
#define WS_NEED    (WS_META_OFF + WS_META_SZ)         // ~176.4 MB (unchanged)

__device__ __forceinline__ unsigned short f2bfu(float f) {
    unsigned u = __float_as_uint(f);
    unsigned r = (u + 0x7fffu + ((u >> 16) & 1u)) >> 16;   // RNE
    return (unsigned short)r;
}
__device__ __forceinline__ unsigned pack2(float lo, float hi) {
    return (unsigned)f2bfu(lo) | ((unsigned)f2bfu(hi) << 16);
}
__device__ __forceinline__ void gload16(const void* g, void* l) {
    __builtin_amdgcn_global_load_lds((const __attribute__((address_space(1))) void*)g,
                                     (__attribute__((address_space(3))) void*)l, 16, 0, 0);
}

__device__ __forceinline__ uint4 make_meta(int pr, int t, float dy, float dx) {
    int oh = pr / WW, ow = pr - oh * WW;
    float py = (float)(oh - 1 + t / 3) + dy;
    float px = (float)(ow - 1 + (t % 3)) + dx;
    float y0f = floorf(py), x0f = floorf(px);
    int y0 = (int)y0f, x0 = (int)x0f;
    float ly = py - y0f, lx = px - x0f;
    float wy0 = (y0 >= 0 && y0 < HH) ? 1.f - ly : 0.f;
    float wy1 = (y0 + 1 >= 0 && y0 + 1 < HH) ? ly : 0.f;
    float u0 = (x0 >= 0 && x0 < WW) ? 1.f - lx : 0.f;
    float u1 = (x0 + 1 >= 0 && x0 + 1 < WW) ? lx : 0.f;
    int pb = min(max(x0, 0), WW - 2);
    float s0, s1;
    if (x0 < 0)           { s0 = u1; s1 = 0.f; }
    else if (x0 > WW - 2) { s0 = 0.f; s1 = u0; }
    else                  { s0 = u0; s1 = u1; }
    int cy0 = min(max(y0, 0), HH - 1);
    int cy1 = min(max(y0 + 1, 0), HH - 1);
    uint4 m;
    m.x = (unsigned)(cy0 * WW + pb);
    m.y = (unsigned)(cy1 * WW + pb);
    m.z = pack2(wy0 * s0, wy0 * s1);
    m.w = pack2(wy1 * s0, wy1 * s1);
    return m;
}

// ================= SPLIT PATH =================

// ---- Kernel A0: w_off -> per-chunk 4KB LDS images (bf16, swizzled, rows 18..31 zero) ----
__global__ __launch_bounds__(256)
void woff_kernel(const float* __restrict__ w_off, char* __restrict__ Woff_b)
{
    int kc  = blockIdx.x;        // 36
    int tid = threadIdx.x;       // 256
    int so  = tid >> 3, sq = tid & 7;
    int tap = kc >> 2, cb = (kc & 3) * 64;
    uint4 pk; pk.x = pk.y = pk.z = pk.w = 0u;
    if (so < OFFC) {
        const float* wr = w_off + (size_t)so * KDIM + (size_t)(cb + sq * 8) * 9 + tap;
        float wv[8];
        #pragma unroll
        for (int i = 0; i < 8; ++i) wv[i] = wr[i * 9];
        pk.x = pack2(wv[0], wv[1]); pk.y = pack2(wv[2], wv[3]);
        pk.z = pack2(wv[4], wv[5]); pk.w = pack2(wv[6], wv[7]);
    }
    *(uint4*)(Woff_b + (size_t)kc * 4096 + so * 128 + ((sq * 16) ^ ((so & 7) << 4))) = pk;
}

// ---- Kernel A: offset conv via MFMA, 512 threads (8 waves), DMA'd W ----
__global__ __launch_bounds__(512)
void offset_meta_kernel2(const float* __restrict__ x,
                         const char* __restrict__ Woff_b,
                         const float* __restrict__ b_off,
                         unsigned* __restrict__ meta2_ws)
{
    __shared__ __align__(16) char Asw[64 * 128];
    __shared__ __align__(16) char Wl[32 * 128];
    __shared__ float Dsh[64][21];

    const int tid = threadIdx.x;
    const int fin = ((blockIdx.x & 7) * 72) + (blockIdx.x >> 3);  // XCD-chunked (576 = 8*72)
    const int b   = fin / 144;
    const int pr0 = (fin % 144) * 64;
    const float* xb = x + (size_t)b * CC * HW;

    const int w    = tid >> 6;      // wave 0..7
    const int l15  = tid & 15;
    const int l4   = (tid >> 4) & 3;
    const int pf   = w & 3;         // p-frag
    const int of   = w >> 2;        // oc-frag
    const int sp   = tid & 63;      // A staging: p row
    const int kq   = tid >> 6;      // A staging: c octet 0..7

    const int prg = pr0 + sp;
    const int oh = prg / WW, ow = prg - (prg / WW) * WW;

    f32x4 acc = (f32x4){0.f, 0.f, 0.f, 0.f};

    for (int kc = 0; kc < NKC; ++kc) {
        const int tap = kc >> 2;
        const int cb  = (kc & 3) * 64;
        // W stage: linear DMA copy of prebuilt image (waves 0..3, 1KB each)
        if (w < 4)
            gload16(Woff_b + (size_t)kc * 4096 + (size_t)tid * 16, Wl + w * 1024);
        // A stage: 8 c per thread, fixed tap -> bounds once, coalesced over p
        {
            int iy = oh + tap / 3 - 1;
            int ix = ow + tap % 3 - 1;
            bool ok = (iy >= 0) & (iy < HH) & (ix >= 0) & (ix < WW);
            const float* xp = xb + (size_t)(cb + kq * 8) * HW + iy * WW + ix;
            float v[8];
            #pragma unroll
            for (int e = 0; e < 8; ++e)
                v[e] = ok ? xp[(size_t)e * HW] : 0.f;
            uint4 pk;
            pk.x = pack2(v[0], v[1]); pk.y = pack2(v[2], v[3]);
            pk.z = pack2(v[4], v[5]); pk.w = pack2(v[6], v[7]);
            *(uint4*)(Asw + sp * 128 + ((kq * 16) ^ ((sp & 7) << 4))) = pk;
        }
        __syncthreads();
        // MFMA: wave (pf, of), 2 k-steps
        {
            int p_loc = pf * 16 + l15;
            unsigned aswz = (unsigned)((p_loc & 7) << 4);
            int o_loc = of * 16 + l15;
            unsigned oswz = (unsigned)((o_loc & 7) << 4);
            #pragma unroll
            for (int ks = 0; ks < 2; ++ks) {
                bf16x8 a  = *(const bf16x8*)(Asw + p_loc * 128 + ((ks * 64 + l4 * 16) ^ aswz));
                bf16x8 bw = *(const bf16x8*)(Wl + o_loc * 128 + ((ks * 64 + l4 * 16) ^ oswz));
                acc = __builtin_amdgcn_mfma_f32_16x16x32_bf16(a, bw, acc, 0, 0, 0);
            }
        }
        __syncthreads();
    }

    // D -> LDS (rows p, cols oc<18), add bias
    {
        int o = of * 16 + l15;
        if (o < OFFC) {
            float bo = b_off[o];
            #pragma unroll
            for (int r = 0; r < 4; ++r)
                Dsh[pf * 16 + l4 * 4 + r][o] = acc[r] + bo;
        }
    }
    __syncthreads();
    for (int s = tid; s < 9 * 64; s += 512) {
        int t = s >> 6, pl = s & 63;
        int pr = pr0 + pl;
        float dy = Dsh[pl][2 * t];
        float dx = Dsh[pl][2 * t + 1];
        unsigned lo = (unsigned)__half_as_ushort(__float2half(dy));
        unsigned hi = (unsigned)__half_as_ushort(__float2half(dx));
        meta2_ws[((size_t)b * 9 + t) * HW + pr] = lo | (hi << 16);
    }
}

// ---- Kernel B: w_dc fp32 -> bf16 pre-swizzled, k' = tap*256 + c ----
__global__ __launch_bounds__(256)
void wconv_kernel(const float* __restrict__ w_dc, char* __restrict__ wb)
{
    int idx = blockIdx.x * 256 + (int)threadIdx.x;   // 73728
    int o   = idx / 288;
    int rem = idx - o * 288;
    int ch  = rem >> 3;          // chunk 0..35
    int q   = rem & 7;           // q group
    int tap = ch >> 2;
    int c0  = (ch & 3) * 64 + q * 8;
    const float* wr = w_dc + (size_t)o * KDIM + (size_t)c0 * 9 + tap;
    float wv[8];
    #pragma unroll
    for (int i = 0; i < 8; ++i) wv[i] = wr[i * 9];
    uint4 pk;
    pk.x = pack2(wv[0], wv[1]); pk.y = pack2(wv[2], wv[3]);
    pk.z = pack2(wv[4], wv[5]); pk.w = pack2(wv[6], wv[7]);
    *(uint4*)(wb + (size_t)o * 4608 + ch * 128 + ((q * 16) ^ ((o & 7) << 4))) = pk;
}

// ---- Kernel C: 9-tap row-shared gather, channel-interleaved bf16 LDS tile ----
#define GT_P   576
#define GT_WIN 14
__global__ __launch_bounds__(512, 4)
void gather_kernel9(const float* __restrict__ x,
                    const unsigned* __restrict__ meta2,
                    char* __restrict__ Vg)
{
    __shared__ __align__(16) unsigned short Xs[GT_WIN * 2 * 100 * 8]; // 44.8KB
    __shared__ unsigned Md[9 * GT_P];                                // 20.7KB

    int bid  = blockIdx.x;                    // 1024 = 8 * 128
    int fin  = (bid & 7) * 128 + (bid >> 3);  // XCD-chunked
    int tile = fin >> 4;                      // 0..63 (b*16 + trow)
    int cq   = fin & 15;                      // 0..15 (16ch each)
    int b    = tile >> 4;
    int h0   = (tile & 15) * 6;
    int c0   = cq * 16;
    int tid  = threadIdx.x;
    int prow0 = tile * GT_P;

    int r0 = h0 - 3; r0 = r0 < 0 ? 0 : (r0 > 82 ? 82 : r0);   // staged rows [r0, r0+13]

    for (int s = tid; s < 9 * GT_P; s += 512) {
        int t = s / GT_P, pl = s - t * GT_P;
        Md[s] = meta2[((size_t)b * 9 + t) * HW + h0 * WW + pl];
    }

    // stage: unit = (row, chh, col) -> 8 ch bf16 packed, one ds_write_b128
    const float* xb = x + ((size_t)b * CC + c0) * HW + r0 * WW;
    for (int s = tid; s < GT_WIN * 2 * 96; s += 512) {
        int col = s % 96;
        int rem = s / 96;
        int chh = rem & 1;
        int row = rem >> 1;
        const float* g = xb + (size_t)(chh * 8) * HW + row * WW + col;
        uint4 pk;
        pk.x = pack2(g[0],              g[(size_t)1 * HW]);
        pk.y = pack2(g[(size_t)2 * HW], g[(size_t)3 * HW]);
        pk.z = pack2(g[(size_t)4 * HW], g[(size_t)5 * HW]);
        pk.w = pack2(g[(size_t)6 * HW], g[(size_t)7 * HW]);
        *(uint4*)&Xs[(((row * 2 + chh) * 100) + col) * 8] = pk;
    }
    __syncthreads();

    const int chh  = tid & 1;                 // 8-ch slot
    const int lsub = (tid & 63) >> 1;         // 0..31 positions per wave
    const int w    = tid >> 6;                // wave 0..7
    const float* xg = x + ((size_t)b * CC + c0 + chh * 8) * HW;  // slow-path base
    const int chunk_hi = (cq >> 2) * 128;     // chunk within tap region
    const int base_in_chunk = (cq & 3) * 32 + chh * 16;

    for (int pass = 0; pass < 3; ++pass) {
        int i = pass * 256 + w * 32 + lsub;
        if (i >= GT_P) break;
        int oh = h0 + i / WW, ow = i - (i / WW) * WW;
        char* vrow0 = Vg + (size_t)(prow0 + i) * 4608;
        const int inchunk = base_in_chunk ^ ((i & 7) << 4);   // 3-bit content swizzle
        #pragma unroll
        for (int t = 0; t < 9; ++t) {
            unsigned md = Md[t * GT_P + i];
            float dy = __half2float(__ushort_as_half((unsigned short)(md & 0xffffu)));
            float dx = __half2float(__ushort_as_half((unsigned short)(md >> 16)));
            float py = (float)(oh - 1 + t / 3) + dy;
            float px = (float)(ow - 1 + t % 3) + dx;
            float y0f = floorf(py), x0f = floorf(px);
            int y0 = (int)y0f, x0 = (int)x0f;
            float ly = py - y0f, lx = px - x0f;
            float wy0 = (y0 >= 0 && y0 < HH) ? 1.f - ly : 0.f;
            float wy1 = (y0 + 1 >= 0 && y0 + 1 < HH) ? ly : 0.f;
            float u0 = (x0 >= 0 && x0 < WW) ? 1.f - lx : 0.f;
            float u1 = (x0 + 1 >= 0 && x0 + 1 < WW) ? lx : 0.f;
            int pb = min(max(x0, 0), WW - 2);
            float s0, s1;
            if (x0 < 0)           { s0 = u1; s1 = 0.f; }
            else if (x0 > WW - 2) { s0 = 0.f; s1 = u0; }
            else                  { s0 = u0; s1 = u1; }
            int cy0 = min(max(y0, 0), HH - 1);
            int cy1 = min(max(y0 + 1, 0), HH - 1);
            float wa0 = wy0 * s0, wa1 = wy0 * s1;
            float wb0 = wy1 * s0, wb1 = wy1 * s1;
            float v[8];
            if (cy0 >= r0 && cy1 <= r0 + GT_WIN - 1) {
                int ra = ((cy0 - r0) * 2 + chh) * 100;
                int rb = ((cy1 - r0) * 2 + chh) * 100;
                u32x4 a0 = *(const u32x4*)&Xs[(ra + pb) * 8];
                u32x4 a1 = *(const u32x4*)&Xs[(ra + pb + 1) * 8];
                u32x4 b0 = *(const u32x4*)&Xs[(rb + pb) * 8];
                u32x4 b1 = *(const u32x4*)&Xs[(rb + pb + 1) * 8];
                #pragma unroll
                for (int k = 0; k < 8; ++k) {
                    unsigned sa0 = a0[k >> 1], sa1 = a1[k >> 1];
                    unsigned sb0 = b0[k >> 1], sb1 = b1[k >> 1];
                    float A0 = __uint_as_float((k & 1) ? (sa0 & 0xffff0000u) : (sa0 << 16));
                    float A1 = __uint_as_float((k & 1) ? (sa1 & 0xffff0000u) : (sa1 << 16));
                    float B0 = __uint_as_float((k & 1) ? (sb0 & 0xffff0000u) : (sb0 << 16));
                    float B1 = __uint_as_float((k & 1) ? (sb1 & 0xffff0000u) : (sb1 << 16));
                    v[k] = fmaf(wa0, A0, fmaf(wa1, A1, fmaf(wb0, B0, wb1 * B1)));
                }
            } else {                                   // rare exact fallback
                const float* pa = xg + cy0 * WW + pb;
                const float* pq = xg + cy1 * WW + pb;
                #pragma unroll
                for (int k = 0; k < 8; ++k) {
                    float A0 = pa[(size_t)k * HW], A1 = pa[(size_t)k * HW + 1];
                    float B0 = pq[(size_t)k * HW], B1 = pq[(size_t)k * HW + 1];
                    v[k] = fmaf(wa0, A0, fmaf(wa1, A1, fmaf(wb0, B0, wb1 * B1)));
                }
            }
            u32x4 pk;
            pk.x = pack2(v[0], v[1]); pk.y = pack2(v[2], v[3]);
            pk.z = pack2(v[4], v[5]); pk.w = pack2(v[6], v[7]);
            *(u32x4*)(vrow0 + t * 512 + chunk_hi + inchunk) = pk;
        }
    }
}

// ---- Kernel D: streaming GEMM, 512 threads, counted-vmcnt 2-deep pipeline ----
// T4: prologue stages chunks 0,1; per iter: s_waitcnt vmcnt(4) (oldest 4 of
// this wave's 8 DMA ops = current chunk), raw s_barrier, MFMA, s_barrier
// (read-complete), STAGE(t+2). Loads never drain to 0 mid-loop.
__global__ __launch_bounds__(512)
void gemm_kernel(const char* __restrict__ Vg, const char* __restrict__ Wb,
                 const float* __restrict__ b_dc, float* __restrict__ out)
{
    __shared__ __align__(16) char Ab[2][128 * 128];
    __shared__ __align__(16) char Bb[2][128 * 128];

    int bid = blockIdx.x;
    int swzb = (bid & 7) * 72 + (bid >> 3);   // both ot of a pt share an XCD
    int pt = swzb >> 1, ot = swzb & 1;
    int tid = threadIdx.x;
    int wav = tid >> 6;                       // 0..7
    const int l15 = tid & 15, l4 = (tid >> 4) & 3;
    const int wp = wav >> 2, wo = wav & 3;    // p-half (64), o-quarter (32)

    const char* Ag = Vg + (size_t)(pt * 128) * 4608;
    const char* Bg = Wb + (size_t)(ot * 128) * 4608;

    f32x4 acc[4][2];
    #pragma unroll
    for (int f = 0; f < 4; ++f)
        #pragma unroll
        for (int g = 0; g < 2; ++g)
            acc[f][g] = (f32x4){0.f, 0.f, 0.f, 0.f};

#define STAGE(bufi, t) {                                                         \
        const char* ag = Ag + (size_t)(t) * 128;                                 \
        const char* bg = Bg + (size_t)(t) * 128;                                 \
        _Pragma("unroll")                                                        \
        for (int i = 0; i < 2; ++i) {                                            \
            int u = i * 512 + tid;                                               \
            int row = u >> 3, cu = (u & 7) * 16;                                 \
            gload16(ag + (size_t)row * 4608 + cu,                                \
                    &Ab[bufi][(i * 512 + wav * 64) * 16]);                       \
            gload16(bg + (size_t)row * 4608 + cu,                                \
                    &Bb[bufi][(i * 512 + wav * 64) * 16]);                       \
        } }

    STAGE(0, 0);
    STAGE(1, 1);

    for (int t = 0; t < NKC; ++t) {
        int cb = t & 1;
        // wait for THIS chunk's 4 DMA ops (oldest); next chunk's stay in flight
        if (t < NKC - 1) {
            asm volatile("s_waitcnt vmcnt(4)" ::: "memory");
        } else {
            asm volatile("s_waitcnt vmcnt(0)" ::: "memory");
        }
        __builtin_amdgcn_s_barrier();          // all waves' chunk-t data in LDS
        asm volatile("" ::: "memory");
        #pragma unroll
        for (int ks = 0; ks < 2; ++ks) {
            bf16x8 a[4], bw[2];
            #pragma unroll
            for (int f = 0; f < 4; ++f) {
                int p_loc = wp * 64 + f * 16 + l15;
                a[f] = *(const bf16x8*)(Ab[cb] + p_loc * 128 +
                                        ((ks * 64 + l4 * 16) ^ ((p_loc & 7) << 4)));
            }
            #pragma unroll
            for (int g = 0; g < 2; ++g) {
                int o_loc = wo * 32 + g * 16 + l15;
                bw[g] = *(const bf16x8*)(Bb[cb] + o_loc * 128 +
                                         ((ks * 64 + l4 * 16) ^ ((o_loc & 7) << 4)));
            }
            #pragma unroll
            for (int f = 0; f < 4; ++f)
                #pragma unroll
                for (int g = 0; g < 2; ++g)
                    acc[f][g] = __builtin_amdgcn_mfma_f32_16x16x32_bf16(a[f], bw[g], acc[f][g], 0, 0, 0);
        }
        asm volatile("s_waitcnt lgkmcnt(0)" ::: "memory");  // all reads of buf cb done
        __builtin_amdgcn_s_barrier();          // every wave finished reading cb
        asm volatile("" ::: "memory");
        if (t + 2 < NKC) STAGE(cb, t + 2);     // overwrite freed buffer
    }
#undef STAGE

    int b = pt / 72;
    int posr = (pt - b * 72) * 128;
    #pragma unroll
    for (int g = 0; g < 2; ++g) {
        int og = ot * 128 + wo * 32 + g * 16 + l15;
        float bias = b_dc[og];
        float* op = out + ((size_t)b * OO + og) * HW + posr + wp * 64 + l4 * 4;
        #pragma unroll
        for (int f = 0; f < 4; ++f) {
            f32x4 r = acc[f][g];
            float4 st;
            st.x = r[0] + bias; st.y = r[1] + bias;
            st.z = r[2] + bias; st.w = r[3] + bias;
            *(float4*)(op + f * 16) = st;
        }
    }
}

// ================= FALLBACK PATH (round-2, verified) =================

__global__ __launch_bounds__(256)
void offset_conv6_kernel(const float* __restrict__ x,
                         const float* __restrict__ w_off,
                         const float* __restrict__ b_off,
                         float* __restrict__ off)
{
    int bid   = blockIdx.x;
    int g     = bid % 3;
    int chunk = (bid / 3) % 36;
    int b     = bid / 108;
    int ocb   = g * 6;
    int pr    = chunk * 256 + (int)threadIdx.x;
    int oh    = pr / WW, ow = pr % WW;
    const float* xb = x + (size_t)b * CC * HW;

    float acc[6];
    #pragma unroll
    for (int i = 0; i < 6; ++i) acc[i] = b_off[ocb + i];

    bool interior = (oh >= 1) & (oh < HH - 1) & (ow >= 1) & (ow < WW - 1);
    if (interior) {
        const float* xp = xb + (oh - 1) * WW + (ow - 1);
        float xv[9];
        #pragma unroll
        for (int t = 0; t < 9; ++t) xv[t] = xp[(t / 3) * WW + (t % 3)];
        for (int c = 0; c < CC; ++c) {
            float xn[9];
            if (c + 1 < CC) {
                const float* xq = xp + (size_t)(c + 1) * HW;
                #pragma unroll
                for (int t = 0; t < 9; ++t) xn[t] = xq[(t / 3) * WW + (t % 3)];
            }
            #pragma unroll
            for (int i = 0; i < 6; ++i) {
                const float* wr = w_off + ((size_t)(ocb + i) * CC + c) * 9;
                #pragma unroll
                for (int t = 0; t < 9; ++t)
                    acc[i] = fmaf(xv[t], wr[t], acc[i]);
            }
            #pragma unroll
            for (int t = 0; t < 9; ++t) xv[t] = xn[t];
        }
    } else {
        for (int c = 0; c < CC; ++c) {
            const float* xc = xb + (size_t)c * HW;
            float xv[9];
            #pragma unroll
            for (int t = 0; t < 9; ++t) {
                int yy = oh + t / 3 - 1, xx = ow + t % 3 - 1;
                xv[t] = (yy >= 0 && yy < HH && xx >= 0 && xx < WW) ? xc[yy * WW + xx] : 0.f;
            }
            #pragma unroll
            for (int i = 0; i < 6; ++i) {
                const float* wr = w_off + ((size_t)(ocb + i) * CC + c) * 9;
                #pragma unroll
                for (int t = 0; t < 9; ++t)
                    acc[i] = fmaf(xv[t], wr[t], acc[i]);
            }
        }
    }
    #pragma unroll
    for (int i = 0; i < 6; ++i)
        off[((size_t)b * OFFC + ocb + i) * HW + pr] = acc[i];
}

__global__ __launch_bounds__(256)
void deform_mfma_kernel(const float* __restrict__ x,
                        const float* __restrict__ off,
                        const float* __restrict__ w_dc,
                        const float* __restrict__ b_dc,
                        float* __restrict__ out)
{
    __shared__ __align__(16) char VlB[128 * 128];
    __shared__ __align__(16) char WlB[128 * 128];
    __shared__ uint4 meta[9][128];

    const int tid  = threadIdx.x;
    const int ot   = blockIdx.x / 288;
    const int pt   = blockIdx.x % 288;
    const int pos0 = pt * 128;
    const int b    = pos0 / HW;
    const int posr = pos0 - b * HW;

    const float* offp = off + (size_t)b * OFFC * HW;
    for (int s = tid; s < 9 * 128; s += 256) {
        int tt = s >> 7, j = s & 127;
        int pr = posr + j;
        float dy = offp[(2 * tt) * HW + pr];
        float dx = offp[(2 * tt + 1) * HW + pr];
        meta[tt][j] = make_meta(pr, tt, dy, dx);
    }
    __syncthreads();

    const int l15 = tid & 15;
    const int l4  = (tid >> 4) & 3;
    const int wav = tid >> 6;
    const int wp  = wav >> 1, wwo = wav & 1;
    const int j     = tid & 127;
    const int khalf = tid >> 7;
    const int wo_o  = tid >> 4;
    const int wk    = (tid & 15) * 4;

    const float* wbase = w_dc + (size_t)(ot * 128) * KDIM;

    f32x4 acc[4][4];
    #pragma unroll
    for (int f = 0; f < 4; ++f)
        #pragma unroll
        for (int g = 0; g < 4; ++g)
            acc[f][g] = (f32x4){0.f, 0.f, 0.f, 0.f};

    for (int k0 = 0; k0 < KDIM; k0 += 64) {
        #pragma unroll
        for (int r = 0; r < 8; ++r) {
            int o = r * 16 + wo_o;
            const float4 wv = *(const float4*)(wbase + (size_t)o * KDIM + k0 + wk);
            uint2 u;
            u.x = pack2(wv.x, wv.y);
            u.y = pack2(wv.z, wv.w);
            *(uint2*)(WlB + o * 128 + ((wk * 2) ^ ((o & 7) << 4))) = u;
        }
        {
            unsigned kb = (unsigned)(k0 + khalf * 32);
            unsigned c  = kb / 9u;
            unsigned tt = kb - c * 9u;
            const float* xc = x + (size_t)((unsigned)b * CC + c) * HW;
            char* vrow = VlB + j * 128;
            const unsigned swz = (unsigned)((j & 7) << 4);
            #pragma unroll
            for (int g = 0; g < 4; ++g) {
                float v[8];
                #pragma unroll
                for (int e = 0; e < 8; ++e) {
                    uint4 m = meta[tt][j];
                    float A0 = xc[m.x], A1 = xc[m.x + 1];
                    float B0 = xc[m.y], B1 = xc[m.y + 1];
                    float a0 = __uint_as_float(m.z << 16);
                    float a1 = __uint_as_float(m.z & 0xffff0000u);
                    float b0 = __uint_as_float(m.w << 16);
                    float b1 = __uint_as_float(m.w & 0xffff0000u);
                    v[e] = fmaf(a0, A0, fmaf(a1, A1, fmaf(b0, B0, b1 * B1)));
                    ++tt;
                    if (tt == 9u) { tt = 0u; xc += HW; }
                }
                uint4 pk;
                pk.x = pack2(v[0], v[1]); pk.y = pack2(v[2], v[3]);
                pk.z = pack2(v[4], v[5]); pk.w = pack2(v[6], v[7]);
                *(uint4*)(vrow + (((unsigned)(khalf * 64 + g * 16)) ^ swz)) = pk;
            }
        }
        __syncthreads();

        #pragma unroll
        for (int ks = 0; ks < 2; ++ks) {
            bf16x8 a[4], bw[4];
            #pragma unroll
            for (int f = 0; f < 4; ++f) {
                int p_loc = wp * 64 + f * 16 + l15;
                a[f] = *(const bf16x8*)(VlB + p_loc * 128 +
                                        ((ks * 64 + l4 * 16) ^ ((p_loc & 7) << 4)));
            }
            #pragma unroll
            for (int g = 0; g < 4; ++g) {
                int o_loc = wwo * 64 + g * 16 + l15;
                bw[g] = *(const bf16x8*)(WlB + o_loc * 128 +
                                         ((ks * 64 + l4 * 16) ^ ((o_loc & 7) << 4)));
            }
            #pragma unroll
            for (int f = 0; f < 4; ++f)
                #pragma unroll
                for (int g = 0; g < 4; ++g)
                    acc[f][g] = __builtin_amdgcn_mfma_f32_16x16x32_bf16(a[f], bw[g], acc[f][g], 0, 0, 0);
        }
        __syncthreads();
    }

    #pragma unroll
    for (int g = 0; g < 4; ++g) {
        int og = ot * 128 + wwo * 64 + g * 16 + l15;
        float bias = b_dc[og];
        float* op = out + ((size_t)b * OO + og) * HW + posr + wp * 64 + l4 * 4;
        #pragma unroll
        for (int f = 0; f < 4; ++f) {
            f32x4 r = acc[f][g];
            float4 st;
            st.x = r[0] + bias; st.y = r[1] + bias;
            st.z = r[2] + bias; st.w = r[3] + bias;
            *(float4*)(op + f * 16) = st;
        }
    }
}

extern "C" void kernel_launch(void* const* d_in, const int* in_sizes, int n_in,
                              void* d_out, int out_size, void* d_ws, size_t ws_size,
                              hipStream_t stream)
{
    const float* x     = (const float*)d_in[0];
    const float* w_off = (const float*)d_in[1];
    const float* b_off = (const float*)d_in[2];
    const float* w_dc  = (const float*)d_in[3];
    const float* b_dc  = (const float*)d_in[4];
    float* out = (float*)d_out;

    if (ws_size >= WS_NEED) {
        char*     ws    = (char*)d_ws;
        char*     Vg    = ws;
        char*     Wb    = ws + WS_WB_OFF;
        unsigned* meta2 = (unsigned*)(ws + WS_META_OFF);
        char*     Woffb = ws + WS_WOFF_OFF;
        woff_kernel<<<NKC, 256, 0, stream>>>(w_off, Woffb);
        wconv_kernel<<<288, 256, 0, stream>>>(w_dc, Wb);
        offset_meta_kernel2<<<576, 512, 0, stream>>>(x, Woffb, b_off, meta2);
        gather_kernel9<<<1024, 512, 0, stream>>>(x, meta2, Vg);
        gemm_kernel<<<576, 512, 0, stream>>>(Vg, Wb, b_dc, out);
    } else {
        float* off = (float*)d_ws;
        offset_conv6_kernel<<<BB * 36 * 3, 256, 0, stream>>>(x, w_off, b_off, off);
        deform_mfma_kernel<<<(OO / 128) * (BB * HW / 128), 256, 0, stream>>>(x, off, w_dc, b_dc, out);
    }
}